// Round 9
// baseline (267.601 us; speedup 1.0000x reference)
//
#include <hip/hip_runtime.h>
#include <cstddef>
#include <cstdint>

// ---------------------------------------------------------------------------
// Pipeline: x (64,3,64,64) -> conv1 5x5s2 (MFMA polyphase) -> GDN1 (MFMA)
//   -> conv2 5x5s2 (MFMA polyphase) -> GDN2 (MFMA) -> conv3 3x3 (MFMA, bf16)
//   -> attn_mega: LN(q)+LN(kv) -> QKV proj -> Bahdanau attention -> outproj
//      + residual + LN + transpose, all in one kernel.  7 launches.
// ---------------------------------------------------------------------------

typedef __bf16 bf16x8 __attribute__((ext_vector_type(8)));
typedef float floatx4 __attribute__((ext_vector_type(4)));
typedef unsigned short ushortT;
typedef unsigned short ushort8v __attribute__((ext_vector_type(8)));

#if __has_builtin(__builtin_amdgcn_exp2f)
#define EXP2F(x) __builtin_amdgcn_exp2f(x)
#else
#define EXP2F(x) exp2f(x)
#endif
#if __has_builtin(__builtin_amdgcn_rcpf)
#define RCPF(x) __builtin_amdgcn_rcpf(x)
#else
#define RCPF(x) (1.f / (x))
#endif

__device__ __forceinline__ ushortT f2bf(float f) {
  unsigned u = __builtin_bit_cast(unsigned, f);
  unsigned r = (u + 0x7FFFu + ((u >> 16) & 1u)) >> 16;
  return (ushortT)r;
}
__device__ __forceinline__ float bf2f(ushortT u) {
  return __builtin_bit_cast(float, ((unsigned)u) << 16);
}

// ---- workspace layout (float-slot offsets) ----
static constexpr size_t OFF_T1BF = 0;          // conv1 out bf16 (64,1024,128)
static constexpr size_t OFF_X2BF = 4194304;    // gdn1 out bf16 [b][4][256][128]
static constexpr size_t OFF_T2BF = 8388608;    // conv2 out bf16 (64,256,128)
static constexpr size_t OFF_X3BF = 9437184;    // gdn2 out bf16 (64,256,128)
static constexpr size_t OFF_QRAW = 10485760;   // conv3 out bf16 (64,256,192)
static constexpr size_t OFF_WBQ  = 21299200;   // bf16 128x192 (scaled by c)
static constexpr size_t OFF_WBK  = 21311488;   // bf16 128x192 (scaled by c)
static constexpr size_t OFF_WBV  = 21323776;   // bf16 192x192
static constexpr size_t OFF_WBO  = 21342208;   // bf16 192x192
static constexpr size_t OFF_WT2  = 26079232;   // bf16 conv2 slabs [200][2048]
static constexpr size_t OFF_WT3  = 26284032;   // bf16 conv3 slabs [108][2048]
static constexpr size_t OFF_WC1  = 26394624;   // bf16 conv1 slabs [5][128][32]
static constexpr size_t OFF_GB1  = 26406912;   // bf16 gamma1 128x128
static constexpr size_t OFF_GB2  = 26415104;   // bf16 gamma2 128x128

// 5x5 s2 p2 polyphase tap tables (tap id = kh*5+kw); HW-verified via conv2.
__device__ __constant__ int d_TWI2[4][9] = {{ 0, 2, 4,10,12,14,20,22,24},
                                            { 1, 3,11,13,21,23, 0, 0, 0},
                                            { 5, 7, 9,15,17,19, 0, 0, 0},
                                            { 6, 8,16,18, 0, 0, 0, 0, 0}};
__device__ __constant__ int d_NT2[4] = {9, 6, 6, 4};

// ---------------------------------------------------------------------------
// fused prep: all weight repacks/casts in one launch, block-range dispatch.
// ---------------------------------------------------------------------------
__device__ void dev_convw3(const float* w, ushortT* wt, int mode, int total,
                           int idx) {
  if (idx >= total) return;
  int j    = idx & 7;
  int om   = (idx >> 3) & 63;
  int kg   = (idx >> 9) & 3;
  int slab = idx >> 11;
  int mt, s, tap, T;
  if (mode == 0) {
    int ph;
    if (slab < 72) ph = 0; else if (slab < 120) ph = 1;
    else if (slab < 168) ph = 2; else ph = 3;
    const int st[4] = {0, 72, 120, 168};
    const int ns[4] = {36, 24, 24, 16};
    int rel = slab - st[ph];
    mt = rel / ns[ph]; s = rel % ns[ph];
    tap = d_TWI2[ph][s >> 2]; T = 25;
  } else {
    mt = slab / 36; s = slab % 36; tap = s >> 2; T = 9;
  }
  int cc = s & 3;
  int c  = cc * 32 + kg * 8 + j;
  int oc = mt * 64 + om;
  wt[idx] = f2bf(w[(size_t)(oc * 128 + c) * T + tap]);
}

__device__ void dev_convw1(const float* w, ushortT* wt, int idx) {
  if (idx >= 20480) return;
  int k    = idx & 31;
  int oc   = (idx >> 5) & 127;
  int slab = idx >> 12;
  int ph, i;
  if (slab < 2) { ph = 0; i = slab; } else { ph = slab - 1; i = 0; }
  int kg = k >> 3, jj = k & 7;
  int tidx = i * 8 + jj;
  float val = 0.f;
  if (kg < 3 && tidx < d_NT2[ph]) {
    int tap = d_TWI2[ph][tidx];
    val = w[(size_t)(oc * 3 + kg) * 25 + tap];
  }
  wt[idx] = f2bf(val);
}

__device__ void dev_wcast(const float* w, ushortT* wb, int total, float scale,
                          int idx) {
  if (idx < total) wb[idx] = f2bf(w[idx] * scale);
}

__global__ __launch_bounds__(256) void prep_kernel(
    const float* __restrict__ conv2_w, ushortT* __restrict__ wt2,
    const float* __restrict__ conv3_w, ushortT* __restrict__ wt3,
    const float* __restrict__ conv1_w, ushortT* __restrict__ wc1,
    const float* __restrict__ Wq, ushortT* __restrict__ wbq,
    const float* __restrict__ Wk, ushortT* __restrict__ wbk,
    const float* __restrict__ Wv, ushortT* __restrict__ wbv,
    const float* __restrict__ out_w, ushortT* __restrict__ wbo,
    const float* __restrict__ gamma1, ushortT* __restrict__ gb1,
    const float* __restrict__ gamma2, ushortT* __restrict__ gb2) {
  constexpr float C2LE = 2.88539008177792681f;   // 2*log2(e)
  int blk = blockIdx.x, tid = threadIdx.x;
  if (blk < 1600)      dev_convw3(conv2_w, wt2, 0, 409600, blk * 256 + tid);
  else if (blk < 2464) dev_convw3(conv3_w, wt3, 1, 221184, (blk - 1600) * 256 + tid);
  else if (blk < 2544) dev_convw1(conv1_w, wc1, (blk - 2464) * 256 + tid);
  else if (blk < 2640) dev_wcast(Wq, wbq, 24576, C2LE, (blk - 2544) * 256 + tid);
  else if (blk < 2736) dev_wcast(Wk, wbk, 24576, C2LE, (blk - 2640) * 256 + tid);
  else if (blk < 2880) dev_wcast(Wv, wbv, 36864, 1.f, (blk - 2736) * 256 + tid);
  else if (blk < 3024) dev_wcast(out_w, wbo, 36864, 1.f, (blk - 2880) * 256 + tid);
  else if (blk < 3088) dev_wcast(gamma1, gb1, 16384, 1.f, (blk - 3024) * 256 + tid);
  else                 dev_wcast(gamma2, gb2, 16384, 1.f, (blk - 3088) * 256 + tid);
}

// ---------------------------------------------------------------------------
// conv1 MFMA polyphase: (64,3,64,64) fp32 -> (64,1024px,128c) bf16.
// ---------------------------------------------------------------------------
__global__ __launch_bounds__(256, 1) void conv1_mfma_kernel(
    const float* __restrict__ x, const ushortT* __restrict__ wc1,
    const float* __restrict__ bias, ushortT* __restrict__ outb) {
  int b  = blockIdx.x >> 2;
  int yg = blockIdx.x & 3;
  int y0 = yg * 8;

  int wave = threadIdx.x >> 6;
  int lane = threadIdx.x & 63;
  int ln15 = lane & 15;
  int kg   = lane >> 4;
  int tid  = threadIdx.x;

  __shared__ ushortT simg[4680];
  __shared__ ushortT sA[5 * 128 * 40];

  for (int j = tid; j < 2340; j += 256) ((unsigned*)simg)[j] = 0u;
  __syncthreads();

  int ihBase = 2 * y0 - 2;
  const float* xb = x + (size_t)b * 3 * 4096;
  for (int j = tid; j < 960; j += 256) {
    int q = j & 15;
    int rr = j >> 4;
    int c = rr / 20, ihl = rr % 20;
    int ih = ihBase + ihl;
    if (ih >= 0 && ih < 64) {
      float4 v = *(const float4*)&xb[c * 4096 + ih * 64 + q * 4];
      int pr = ih & 1, u = ih >> 1;
      int lr = u - y0 + 1;
      int base0 = ((pr * 2 + 0) * 3 + c) * 360 + lr * 36;
      int base1 = ((pr * 2 + 1) * 3 + c) * 360 + lr * 36;
      simg[base0 + 2 * q + 1] = f2bf(v.x);
      simg[base1 + 2 * q + 1] = f2bf(v.y);
      simg[base0 + 2 * q + 2] = f2bf(v.z);
      simg[base1 + 2 * q + 2] = f2bf(v.w);
    }
  }
  for (int j = tid; j < 2560; j += 256) {
    int chunk = j & 3, row = j >> 2;
    uint4 v = *(const uint4*)&wc1[row * 32 + chunk * 8];
    *(uint4*)&sA[row * 40 + chunk * 8] = v;
  }
  __syncthreads();

  constexpr int TDR[4][9] = {{-1,-1,-1, 0, 0, 0, 1, 1, 1},
                             {-1,-1, 0, 0, 1, 1, 0, 0, 0},
                             {-1,-1,-1, 0, 0, 0, 0, 0, 0},
                             {-1,-1, 0, 0, 0, 0, 0, 0, 0}};
  constexpr int TDC[4][9] = {{-1, 0, 1,-1, 0, 1,-1, 0, 1},
                             {-1, 0,-1, 0,-1, 0, 0, 0, 0},
                             {-1, 0, 1,-1, 0, 1, 0, 0, 0},
                             {-1, 0,-1, 0, 0, 0, 0, 0, 0}};
  constexpr int NT[4]  = {9, 6, 6, 4};
  constexpr int NM[4]  = {2, 1, 1, 1};
  constexpr int SB[4]  = {0, 2, 3, 4};

  ushort8v Bf[4][5];
  #pragma unroll
  for (int ntl = 0; ntl < 4; ++ntl) {
    int ntg = wave * 4 + ntl;
    int yloc = ntg >> 1;
    int xx = (ntg & 1) * 16 + ln15;
    int lbase = (yloc + 1) * 36 + xx + 1 + kg * 360;
    #pragma unroll
    for (int ph = 0; ph < 4; ++ph) {
      int pbase = ph * 1080 + lbase;
      #pragma unroll
      for (int i = 0; i < 2; ++i) {
        if (i < NM[ph]) {
          ushort8v bv;
          #pragma unroll
          for (int j = 0; j < 8; ++j) {
            int tidx = i * 8 + j;
            if (tidx >= NT[ph]) tidx = 0;
            int off = TDR[ph][tidx] * 36 + TDC[ph][tidx];
            bv[j] = simg[pbase + off];
          }
          Bf[ntl][SB[ph] + i] = bv;
        }
      }
    }
  }

  #pragma unroll
  for (int m = 0; m < 8; ++m) {
    bf16x8 Af[5];
    #pragma unroll
    for (int s = 0; s < 5; ++s)
      Af[s] = *(const bf16x8*)&sA[(s * 128 + m * 16 + ln15) * 40 + kg * 8];
    int oc0 = m * 16 + kg * 4;
    float4 bv = *(const float4*)&bias[oc0];
    #pragma unroll
    for (int ntl = 0; ntl < 4; ++ntl) {
      floatx4 acc = (floatx4)0.f;
      #pragma unroll
      for (int s = 0; s < 5; ++s)
        acc = __builtin_amdgcn_mfma_f32_16x16x32_bf16(
            Af[s], __builtin_bit_cast(bf16x8, Bf[ntl][s]), acc, 0, 0, 0);
      int ntg = wave * 4 + ntl;
      int y = y0 + (ntg >> 1);
      int xx = (ntg & 1) * 16 + ln15;
      int p = y * 32 + xx;
      ushort4 o4 = {f2bf(acc[0] + bv.x), f2bf(acc[1] + bv.y),
                    f2bf(acc[2] + bv.z), f2bf(acc[3] + bv.w)};
      *(ushort4*)&outb[((size_t)b * 1024 + p) * 128 + oc0] = o4;
    }
  }
}

// ---------------------------------------------------------------------------
// GDN as bf16 MFMA GEMM.
// ---------------------------------------------------------------------------
__global__ __launch_bounds__(256) void gdn_mfma_kernel(
    const ushortT* __restrict__ xbf, const ushortT* __restrict__ gb,
    const float* __restrict__ beta, ushortT* __restrict__ ybf,
    int HW, int nPixTiles, int isSplit) {
  int pt = blockIdx.x % nPixTiles;
  int b  = blockIdx.x / nPixTiles;
  int px0 = pt * 64;
  int tid = threadIdx.x;
  int wave = tid >> 6, lane = tid & 63, ln15 = lane & 15, kg = lane >> 4;

  __shared__ ushortT sG[128 * 136];
  __shared__ ushortT sX[64 * 136];

  for (int j = tid; j < 2048; j += 256) {
    int row = j >> 4, ch = j & 15;
    *(uint4*)&sG[row * 136 + ch * 8] = *(const uint4*)&gb[row * 128 + ch * 8];
  }
  for (int j = tid; j < 1024; j += 256) {
    int row = j >> 4, ch = j & 15;
    ushort8v xv = *(const ushort8v*)&xbf[((size_t)(b * HW + px0 + row)) * 128 + ch * 8];
    ushort8v sq;
    #pragma unroll
    for (int r = 0; r < 8; ++r) {
      float f = bf2f(xv[r]);
      sq[r] = f2bf(f * f);
    }
    *(ushort8v*)&sX[row * 136 + ch * 8] = sq;
  }
  __syncthreads();

  floatx4 acc[2][4];
  #pragma unroll
  for (int mi = 0; mi < 2; ++mi)
    #pragma unroll
    for (int nt = 0; nt < 4; ++nt) acc[mi][nt] = (floatx4)0.f;

  #pragma unroll
  for (int k0 = 0; k0 < 128; k0 += 32) {
    bf16x8 a0 = *(const bf16x8*)&sG[(wave * 32 + ln15) * 136 + k0 + kg * 8];
    bf16x8 a1 = *(const bf16x8*)&sG[(wave * 32 + 16 + ln15) * 136 + k0 + kg * 8];
    #pragma unroll
    for (int nt = 0; nt < 4; ++nt) {
      bf16x8 bb = *(const bf16x8*)&sX[(nt * 16 + ln15) * 136 + k0 + kg * 8];
      acc[0][nt] = __builtin_amdgcn_mfma_f32_16x16x32_bf16(a0, bb, acc[0][nt], 0, 0, 0);
      acc[1][nt] = __builtin_amdgcn_mfma_f32_16x16x32_bf16(a1, bb, acc[1][nt], 0, 0, 0);
    }
  }

  #pragma unroll
  for (int mi = 0; mi < 2; ++mi) {
    int d0 = wave * 32 + mi * 16 + kg * 4;
    float4 bt = *(const float4*)&beta[d0];
    #pragma unroll
    for (int nt = 0; nt < 4; ++nt) {
      int p = px0 + nt * 16 + ln15;
      ushort4 x4 = *(const ushort4*)&xbf[((size_t)(b * HW + p)) * 128 + d0];
      ushort4 o4;
      o4.x = f2bf(bf2f(x4.x) * rsqrtf(acc[mi][nt][0] + bt.x));
      o4.y = f2bf(bf2f(x4.y) * rsqrtf(acc[mi][nt][1] + bt.y));
      o4.z = f2bf(bf2f(x4.z) * rsqrtf(acc[mi][nt][2] + bt.z));
      o4.w = f2bf(bf2f(x4.w) * rsqrtf(acc[mi][nt][3] + bt.w));
      size_t dst;
      if (isSplit) {
        int h = p >> 5, w5 = p & 31;
        int ph = ((h & 1) << 1) | (w5 & 1);
        dst = (((size_t)b * 4 + ph) * 256 + (h >> 1) * 16 + (w5 >> 1)) * 128 + d0;
      } else {
        dst = ((size_t)b * 256 + p) * 128 + d0;
      }
      *(ushort4*)&ybf[dst] = o4;
    }
  }
}

// ---------------------------------------------------------------------------
// conv2/conv3 MFMA implicit GEMM; 4-row split, 2 blocks/CU, bf16 out.
// ---------------------------------------------------------------------------
template<int MODE>
__global__ __launch_bounds__(256, 2) void conv_mfma_kernel(
    const ushortT* __restrict__ X,
    const ushortT* __restrict__ Wt,
    const float* __restrict__ bias,
    ushortT* __restrict__ outb) {
  constexpr int OC  = (MODE == 0) ? 128 : 192;
  constexpr int NMT = OC / 64;
  constexpr int NPH = (MODE == 0) ? 4 : 1;

  int b   = blockIdx.x / (NMT * 4);
  int rem = blockIdx.x % (NMT * 4);
  int mt  = rem >> 2;
  int rs  = rem & 3;
  int r0  = rs * 4;

  int wave = threadIdx.x >> 6;
  int lane = threadIdx.x & 63;
  int ln15 = lane & 15;
  int kg   = lane >> 4;

  __shared__ ushortT simg[6 * 18 * 136];

  floatx4 acc[4];
  #pragma unroll
  for (int m = 0; m < 4; ++m) acc[m] = (floatx4)0.f;

  constexpr int NS2[4]      = {36, 24, 24, 16};
  constexpr int PHSTART2[4] = {0, 72, 120, 168};
  constexpr int TDR_2[4][9] = {{-1,-1,-1, 0, 0, 0, 1, 1, 1},
                               {-1,-1, 0, 0, 1, 1, 0, 0, 0},
                               {-1,-1,-1, 0, 0, 0, 0, 0, 0},
                               {-1,-1, 0, 0, 0, 0, 0, 0, 0}};
  constexpr int TDC_2[4][9] = {{-1, 0, 1,-1, 0, 1,-1, 0, 1},
                               {-1, 0,-1, 0,-1, 0, 0, 0, 0},
                               {-1, 0, 1,-1, 0, 1, 0, 0, 0},
                               {-1, 0,-1, 0, 0, 0, 0, 0, 0}};
  constexpr int TDR_3[9] = {-1,-1,-1, 0, 0, 0, 1, 1, 1};
  constexpr int TDC_3[9] = {-1, 0, 1,-1, 0, 1,-1, 0, 1};

  const int aoff = kg * 512 + ln15 * 8;
  uint4 apf[8][4];

  #pragma unroll
  for (int ph = 0; ph < NPH; ++ph) {
    const int NS = (MODE == 0) ? NS2[ph] : 36;
    const int slabBase = (MODE == 0) ? (PHSTART2[ph] + mt * NS2[ph]) : (mt * 36);
    const ushortT* wp0 = Wt + (size_t)slabBase * 2048 + aoff;

    __syncthreads();
    const ushortT* Xb = X + (((size_t)b * NPH + ph) * 256) * 128;
    for (int idx = threadIdx.x; idx < 1728; idx += 256) {
      int chunk = idx & 15;
      int pix = idx >> 4;
      int row = pix / 18, colm = pix - row * 18;
      int i = r0 - 1 + row, j = colm - 1;
      uint4 v = {0u, 0u, 0u, 0u};
      if (i >= 0 && i < 16 && j >= 0 && j < 16)
        v = *(const uint4*)(Xb + ((size_t)(i * 16 + j)) * 128 + chunk * 8);
      *(uint4*)&simg[(row * 18 + colm) * 136 + chunk * 8] = v;
    }
    #pragma unroll
    for (int jj = 0; jj < 8; ++jj)
      if (jj < NS) {
        #pragma unroll
        for (int m = 0; m < 4; ++m)
          apf[jj][m] = *(const uint4*)(wp0 + (size_t)jj * 2048 + m * 128);
      }
    __syncthreads();

    #pragma unroll
    for (int s0 = 0; s0 < NS; s0 += 8) {
      #pragma unroll
      for (int jj = 0; jj < 8; ++jj) {
        int s = s0 + jj;
        if (s < NS) {
          bf16x8 acur[4];
          #pragma unroll
          for (int m = 0; m < 4; ++m) acur[m] = __builtin_bit_cast(bf16x8, apf[jj][m]);
          int sp = s + 8;
          if (sp < NS) {
            #pragma unroll
            for (int m = 0; m < 4; ++m)
              apf[jj][m] = *(const uint4*)(wp0 + (size_t)sp * 2048 + m * 128);
          }
          int t  = s >> 2;
          int c0 = (s & 3) * 32;
          int dr = (MODE == 0) ? TDR_2[ph][t] : TDR_3[t];
          int dc = (MODE == 0) ? TDC_2[ph][t] : TDC_3[t];
          int lrow = wave + dr + 1;
          int lcol = ln15 + dc + 1;
          bf16x8 bfr = *(const bf16x8*)&simg[(lrow * 18 + lcol) * 136 + c0 + kg * 8];
          #pragma unroll
          for (int m = 0; m < 4; ++m)
            acc[m] = __builtin_amdgcn_mfma_f32_16x16x32_bf16(acur[m], bfr, acc[m], 0, 0, 0);
        }
      }
    }
  }

  #pragma unroll
  for (int m = 0; m < 4; ++m) {
    int mg = mt * 64 + m * 16 + kg * 4;
    float4 bv = *(const float4*)&bias[mg];
    int r = r0 + wave;
    int p = r * 16 + ln15;
    ushort4 o4 = {f2bf(acc[m][0] + bv.x), f2bf(acc[m][1] + bv.y),
                  f2bf(acc[m][2] + bv.z), f2bf(acc[m][3] + bv.w)};
    *(ushort4*)&outb[((size_t)b * 256 + p) * OC + mg] = o4;
  }
}

// ---------------------------------------------------------------------------
// attn_mega: the entire post-conv3 back-end in one kernel.
// Block = (b, 64-row q tile). Phase-overlaid 63KB static LDS:
//   QLN  u[ 0    .. 12800)  bf16 [64][200]   (ph1-2)
//   KV   u[12800 .. 19200)  bf16 [32][200]   (ph1-2b)
//   QP   u[19200 .. 27904)  bf16 [64][136]   (ph2-3)
//   KP   u[27904 .. 32256)  bf16 [32][136]   (ph2-3)
//   VP   u[ 0    ..  6400)  bf16 [32][200]   (ph2b-5, over dead QLN)
//   SE   u[ 6400 .. 10624)  f32  [64][33]    (ph3-5)
//   SWM  u[10624 .. 10880)  f32  [128]       (ph2b-3)
//   S0   u[10880 .. 10882)  f32
//   CTX  u[19200 .. 32000)  bf16 [64][200]   (ph5-6, over dead QP/KP)
//   SF   u[ 0    .. 12352)  f32  [32][193]   (ph6, over dead VP/SE/SWM)
// ---------------------------------------------------------------------------
__global__ __launch_bounds__(256) void attn_mega_kernel(
    const ushortT* __restrict__ qrawb, const float* __restrict__ ln_q_w,
    const float* __restrict__ ln_q_b, const float* __restrict__ yg,
    const float* __restrict__ ln_kv_w, const float* __restrict__ ln_kv_b,
    const ushortT* __restrict__ wbq, const ushortT* __restrict__ wbk,
    const ushortT* __restrict__ wbv, const ushortT* __restrict__ wbo,
    const float* __restrict__ vw, const float* __restrict__ out_b,
    const float* __restrict__ ln_out_w, const float* __restrict__ ln_out_b,
    float* __restrict__ out) {
  __shared__ ushortT smem[32256];
  ushortT* sqln = smem;
  ushortT* skv  = smem + 12800;
  ushortT* sqp  = smem + 19200;
  ushortT* skp  = smem + 27904;
  ushortT* svp  = smem;
  float*   se   = (float*)(smem + 6400);
  float*   swm  = (float*)(smem + 10624);
  float*   sS0  = (float*)(smem + 10880);
  ushortT* sctx = smem + 19200;
  float*   sf   = (float*)smem;

  int b  = blockIdx.x >> 2;
  int t0 = (blockIdx.x & 3) * 64;
  int tid  = threadIdx.x;
  int wave = tid >> 6;
  int lane = tid & 63;
  int ln15 = lane & 15;
  int kg   = lane >> 4;

  // ---- ph1: LN(q rows) -> sqln; LN(kv gather) -> skv ----
  for (int r = wave; r < 64; r += 4) {
    const ushortT* xr = qrawb + ((size_t)(b * 256 + t0 + r)) * 192;
    float v0 = bf2f(xr[lane]), v1 = bf2f(xr[lane + 64]), v2 = bf2f(xr[lane + 128]);
    float s = v0 + v1 + v2;
    float s2 = v0 * v0 + v1 * v1 + v2 * v2;
    #pragma unroll
    for (int off = 32; off; off >>= 1) { s += __shfl_xor(s, off); s2 += __shfl_xor(s2, off); }
    float mean = s * (1.f / 192.f);
    float var = s2 * (1.f / 192.f) - mean * mean;
    float inv = rsqrtf(var + 1e-5f);
    sqln[r * 200 + lane]       = f2bf((v0 - mean) * inv * ln_q_w[lane]       + ln_q_b[lane]);
    sqln[r * 200 + lane + 64]  = f2bf((v1 - mean) * inv * ln_q_w[lane + 64]  + ln_q_b[lane + 64]);
    sqln[r * 200 + lane + 128] = f2bf((v2 - mean) * inv * ln_q_w[lane + 128] + ln_q_b[lane + 128]);
  }
  for (int r = wave; r < 32; r += 4) {
    const float* src = yg + (size_t)b * 6144 + r;
    float v0 = src[(size_t)lane * 32];
    float v1 = src[(size_t)(lane + 64) * 32];
    float v2 = src[(size_t)(lane + 128) * 32];
    float s = v0 + v1 + v2;
    float s2 = v0 * v0 + v1 * v1 + v2 * v2;
    #pragma unroll
    for (int off = 32; off; off >>= 1) { s += __shfl_xor(s, off); s2 += __shfl_xor(s2, off); }
    float mean = s * (1.f / 192.f);
    float var = s2 * (1.f / 192.f) - mean * mean;
    float inv = rsqrtf(var + 1e-5f);
    skv[r * 200 + lane]       = f2bf((v0 - mean) * inv * ln_kv_w[lane]       + ln_kv_b[lane]);
    skv[r * 200 + lane + 64]  = f2bf((v1 - mean) * inv * ln_kv_w[lane + 64]  + ln_kv_b[lane + 64]);
    skv[r * 200 + lane + 128] = f2bf((v2 - mean) * inv * ln_kv_w[lane + 128] + ln_kv_b[lane + 128]);
  }
  __syncthreads();

  // ---- ph2: qproj (sqln x wbq -> sqp), kproj (skv x wbk -> skp) ----
  for (int ti = wave; ti < 32; ti += 4) {       // qproj: 4 rt x 8 ct
    int rt = ti >> 3, ct = ti & 7;
    floatx4 acc = (floatx4)0.f;
    #pragma unroll
    for (int k0 = 0; k0 < 192; k0 += 32) {
      bf16x8 afr = *(const bf16x8*)&sqln[(rt * 16 + ln15) * 200 + k0 + kg * 8];
      bf16x8 bfr = *(const bf16x8*)&wbq[((size_t)(ct * 16 + ln15)) * 192 + k0 + kg * 8];
      acc = __builtin_amdgcn_mfma_f32_16x16x32_bf16(afr, bfr, acc, 0, 0, 0);
    }
    #pragma unroll
    for (int r = 0; r < 4; ++r)
      sqp[(rt * 16 + kg * 4 + r) * 136 + ct * 16 + ln15] = f2bf(acc[r]);
  }
  for (int ti = wave; ti < 16; ti += 4) {       // kproj: 2 rt x 8 ct
    int rt = ti >> 3, ct = ti & 7;
    floatx4 acc = (floatx4)0.f;
    #pragma unroll
    for (int k0 = 0; k0 < 192; k0 += 32) {
      bf16x8 afr = *(const bf16x8*)&skv[(rt * 16 + ln15) * 200 + k0 + kg * 8];
      bf16x8 bfr = *(const bf16x8*)&wbk[((size_t)(ct * 16 + ln15)) * 192 + k0 + kg * 8];
      acc = __builtin_amdgcn_mfma_f32_16x16x32_bf16(afr, bfr, acc, 0, 0, 0);
    }
    #pragma unroll
    for (int r = 0; r < 4; ++r)
      skp[(rt * 16 + kg * 4 + r) * 136 + ct * 16 + ln15] = f2bf(acc[r]);
  }
  __syncthreads();

  // ---- ph2b: vproj (skv x wbv -> svp, over dead sqln) + swm/S0 ----
  for (int ti = wave; ti < 24; ti += 4) {       // 2 rt x 12 ct
    int rt = ti / 12, ct = ti % 12;
    floatx4 acc = (floatx4)0.f;
    #pragma unroll
    for (int k0 = 0; k0 < 192; k0 += 32) {
      bf16x8 afr = *(const bf16x8*)&skv[(rt * 16 + ln15) * 200 + k0 + kg * 8];
      bf16x8 bfr = *(const bf16x8*)&wbv[((size_t)(ct * 16 + ln15)) * 192 + k0 + kg * 8];
      acc = __builtin_amdgcn_mfma_f32_16x16x32_bf16(afr, bfr, acc, 0, 0, 0);
    }
    #pragma unroll
    for (int r = 0; r < 4; ++r)
      svp[(rt * 16 + kg * 4 + r) * 200 + ct * 16 + ln15] = f2bf(acc[r]);
  }
  if (tid < 128) swm[tid] = -2.f * vw[tid];
  if (tid < 64) {
    float s = vw[tid] + vw[tid + 64];
    #pragma unroll
    for (int off = 32; off; off >>= 1) s += __shfl_xor(s, off);
    if (tid == 0) *sS0 = s;
  }
  __syncthreads();

  // ---- ph3: energy -> se ----
  {
    float S0v = *sS0;
    int qq0 = tid >> 4, kc = tid & 15;
    const float4* w4 = (const float4*)swm;
    #pragma unroll
    for (int st = 0; st < 4; ++st) {
      int qq = st * 16 + qq0;
      const ushortT* qrow = sqp + qq * 136;
      const ushortT* kr0 = skp + kc * 136;
      const ushortT* kr1 = skp + (kc + 16) * 136;
      float acc0 = S0v, acc1 = S0v;
      #pragma unroll 8
      for (int d4 = 0; d4 < 32; ++d4) {
        ushort4 qu = *(const ushort4*)&qrow[d4 * 4];
        ushort4 k0u = *(const ushort4*)&kr0[d4 * 4];
        ushort4 k1u = *(const ushort4*)&kr1[d4 * 4];
        float4 wv = w4[d4];
        float qx = bf2f(qu.x), qy = bf2f(qu.y), qz = bf2f(qu.z), qw = bf2f(qu.w);
        acc0 += wv.x * RCPF(EXP2F(qx + bf2f(k0u.x)) + 1.f);
        acc0 += wv.y * RCPF(EXP2F(qy + bf2f(k0u.y)) + 1.f);
        acc0 += wv.z * RCPF(EXP2F(qz + bf2f(k0u.z)) + 1.f);
        acc0 += wv.w * RCPF(EXP2F(qw + bf2f(k0u.w)) + 1.f);
        acc1 += wv.x * RCPF(EXP2F(qx + bf2f(k1u.x)) + 1.f);
        acc1 += wv.y * RCPF(EXP2F(qy + bf2f(k1u.y)) + 1.f);
        acc1 += wv.z * RCPF(EXP2F(qz + bf2f(k1u.z)) + 1.f);
        acc1 += wv.w * RCPF(EXP2F(qw + bf2f(k1u.w)) + 1.f);
      }
      se[qq * 33 + kc] = acc0;
      se[qq * 33 + kc + 16] = acc1;
    }
  }
  __syncthreads();

  // ---- ph4: softmax rows ----
  if (tid < 64) {
    float* ser = se + tid * 33;
    float mx = -1e30f;
    for (int k = 0; k < 32; ++k) mx = fmaxf(mx, ser[k]);
    float s = 0.f;
    for (int k = 0; k < 32; ++k) { float a = __expf(ser[k] - mx); ser[k] = a; s += a; }
    float invs = 1.f / s;
    for (int k = 0; k < 32; ++k) ser[k] *= invs;
  }
  __syncthreads();

  // ---- ph5: PV -> sctx (over dead sqp/skp) ----
  for (int j = tid; j < 3072; j += 256) {
    int qq = j / 48, m4 = j % 48;
    const float* al = se + qq * 33;
    float4 a = {0.f, 0.f, 0.f, 0.f};
    #pragma unroll 8
    for (int k = 0; k < 32; ++k) {
      float wk = al[k];
      ushort4 vv = *(const ushort4*)&svp[k * 200 + m4 * 4];
      a.x += wk * bf2f(vv.x); a.y += wk * bf2f(vv.y);
      a.z += wk * bf2f(vv.z); a.w += wk * bf2f(vv.w);
    }
    ushort4 o4 = {f2bf(a.x), f2bf(a.y), f2bf(a.z), f2bf(a.w)};
    *(ushort4*)&sctx[qq * 200 + m4 * 4] = o4;
  }
  __syncthreads();

  // ---- ph6: per 32-row half: outproj -> sf; residual(re-LN)+final LN; store
  for (int hh = 0; hh < 2; ++hh) {
    for (int ti = wave; ti < 24; ti += 4) {     // 2 rt x 12 ct
      int rt = ti / 12, ct = ti % 12;
      floatx4 acc = (floatx4)0.f;
      #pragma unroll
      for (int k0 = 0; k0 < 192; k0 += 32) {
        bf16x8 afr = *(const bf16x8*)&sctx[(hh * 32 + rt * 16 + ln15) * 200 + k0 + kg * 8];
        bf16x8 bfr = *(const bf16x8*)&wbo[((size_t)(ct * 16 + ln15)) * 192 + k0 + kg * 8];
        acc = __builtin_amdgcn_mfma_f32_16x16x32_bf16(afr, bfr, acc, 0, 0, 0);
      }
      float bv = out_b[ct * 16 + ln15];
      #pragma unroll
      for (int r = 0; r < 4; ++r)
        sf[(rt * 16 + kg * 4 + r) * 193 + ct * 16 + ln15] = acc[r] + bv;
    }
    __syncthreads();

    for (int rr = wave; rr < 32; rr += 4) {
      int t = t0 + hh * 32 + rr;
      const ushortT* xr = qrawb + ((size_t)(b * 256 + t)) * 192;
      float r0_ = bf2f(xr[lane]), r1_ = bf2f(xr[lane + 64]), r2_ = bf2f(xr[lane + 128]);
      float s = r0_ + r1_ + r2_;
      float s2 = r0_ * r0_ + r1_ * r1_ + r2_ * r2_;
      #pragma unroll
      for (int off = 32; off; off >>= 1) { s += __shfl_xor(s, off); s2 += __shfl_xor(s2, off); }
      float mean = s * (1.f / 192.f);
      float var = s2 * (1.f / 192.f) - mean * mean;
      float inv = rsqrtf(var + 1e-5f);
      float q0 = (r0_ - mean) * inv * ln_q_w[lane]       + ln_q_b[lane];
      float q1 = (r1_ - mean) * inv * ln_q_w[lane + 64]  + ln_q_b[lane + 64];
      float q2 = (r2_ - mean) * inv * ln_q_w[lane + 128] + ln_q_b[lane + 128];
      float v0 = sf[rr * 193 + lane]       + q0;
      float v1 = sf[rr * 193 + lane + 64]  + q1;
      float v2 = sf[rr * 193 + lane + 128] + q2;
      float t_s = v0 + v1 + v2;
      float t_s2 = v0 * v0 + v1 * v1 + v2 * v2;
      #pragma unroll
      for (int off = 32; off; off >>= 1) { t_s += __shfl_xor(t_s, off); t_s2 += __shfl_xor(t_s2, off); }
      float m2 = t_s * (1.f / 192.f);
      float var2 = t_s2 * (1.f / 192.f) - m2 * m2;
      float inv2 = rsqrtf(var2 + 1e-5f);
      sf[rr * 193 + lane]       = (v0 - m2) * inv2 * ln_out_w[lane]       + ln_out_b[lane];
      sf[rr * 193 + lane + 64]  = (v1 - m2) * inv2 * ln_out_w[lane + 64]  + ln_out_b[lane + 64];
      sf[rr * 193 + lane + 128] = (v2 - m2) * inv2 * ln_out_w[lane + 128] + ln_out_b[lane + 128];
    }
    __syncthreads();

    for (int j = tid; j < 1536; j += 256) {
      int m = j >> 3, t4 = j & 7;
      float4 o4;
      o4.x = sf[(t4 * 4 + 0) * 193 + m];
      o4.y = sf[(t4 * 4 + 1) * 193 + m];
      o4.z = sf[(t4 * 4 + 2) * 193 + m];
      o4.w = sf[(t4 * 4 + 3) * 193 + m];
      *(float4*)&out[((size_t)(b * 192 + m)) * 256 + t0 + hh * 32 + t4 * 4] = o4;
    }
    __syncthreads();
  }
}

// ---------------------------------------------------------------------------
extern "C" void kernel_launch(void* const* d_in, const int* in_sizes, int n_in,
                              void* d_out, int out_size, void* d_ws, size_t ws_size,
                              hipStream_t stream) {
  (void)in_sizes; (void)n_in; (void)out_size; (void)ws_size;
  const float* x_p     = (const float*)d_in[0];
  const float* y_g     = (const float*)d_in[1];
  const float* conv1_w = (const float*)d_in[2];
  const float* conv1_b = (const float*)d_in[3];
  const float* gamma1  = (const float*)d_in[4];
  const float* beta1   = (const float*)d_in[5];
  const float* conv2_w = (const float*)d_in[6];
  const float* conv2_b = (const float*)d_in[7];
  const float* gamma2  = (const float*)d_in[8];
  const float* beta2   = (const float*)d_in[9];
  const float* conv3_w = (const float*)d_in[10];
  const float* conv3_b = (const float*)d_in[11];
  const float* ln_q_w  = (const float*)d_in[12];
  const float* ln_q_b  = (const float*)d_in[13];
  const float* ln_kv_w = (const float*)d_in[14];
  const float* ln_kv_b = (const float*)d_in[15];
  const float* ln_out_w= (const float*)d_in[16];
  const float* ln_out_b= (const float*)d_in[17];
  const float* Wq      = (const float*)d_in[18];
  const float* Wk      = (const float*)d_in[19];
  const float* v_w     = (const float*)d_in[20];
  const float* Wv      = (const float*)d_in[21];
  const float* out_w   = (const float*)d_in[22];
  const float* out_b   = (const float*)d_in[23];
  float* out = (float*)d_out;
  float* ws  = (float*)d_ws;

  ushortT* t1bf  = (ushortT*)(ws + OFF_T1BF);
  ushortT* x2bf  = (ushortT*)(ws + OFF_X2BF);
  ushortT* t2bf  = (ushortT*)(ws + OFF_T2BF);
  ushortT* x3bf  = (ushortT*)(ws + OFF_X3BF);
  ushortT* qrawb = (ushortT*)(ws + OFF_QRAW);
  ushortT* wbq   = (ushortT*)(ws + OFF_WBQ);
  ushortT* wbk   = (ushortT*)(ws + OFF_WBK);
  ushortT* wbv   = (ushortT*)(ws + OFF_WBV);
  ushortT* wbo   = (ushortT*)(ws + OFF_WBO);
  ushortT* wt2   = (ushortT*)(ws + OFF_WT2);
  ushortT* wt3   = (ushortT*)(ws + OFF_WT3);
  ushortT* wc1   = (ushortT*)(ws + OFF_WC1);
  ushortT* gb1   = (ushortT*)(ws + OFF_GB1);
  ushortT* gb2   = (ushortT*)(ws + OFF_GB2);

  prep_kernel<<<3152, 256, 0, stream>>>(conv2_w, wt2, conv3_w, wt3, conv1_w, wc1,
                                        Wq, wbq, Wk, wbk, Wv, wbv, out_w, wbo,
                                        gamma1, gb1, gamma2, gb2);
  conv1_mfma_kernel<<<256, 256, 0, stream>>>(x_p, wc1, conv1_b, t1bf);
  gdn_mfma_kernel<<<1024, 256, 0, stream>>>(t1bf, gb1, beta1, x2bf, 1024, 16, 1);
  conv_mfma_kernel<0><<<512, 256, 0, stream>>>(x2bf, wt2, conv2_b, t2bf);
  gdn_mfma_kernel<<<256, 256, 0, stream>>>(t2bf, gb2, beta2, x3bf, 256, 4, 0);
  conv_mfma_kernel<1><<<768, 256, 0, stream>>>(x3bf, wt3, conv3_b, qrawb);
  attn_mega_kernel<<<256, 256, 0, stream>>>(qrawb, ln_q_w, ln_q_b, y_g,
                                            ln_kv_w, ln_kv_b, wbq, wbk, wbv,
                                            wbo, v_w, out_b, ln_out_w,
                                            ln_out_b, out);
}

// Round 10
// 262.833 us; speedup vs baseline: 1.0181x; 1.0181x over previous
//
#include <hip/hip_runtime.h>
#include <cstddef>
#include <cstdint>

// ---------------------------------------------------------------------------
// Pipeline: x (64,3,64,64) -> conv1 5x5s2 (MFMA polyphase) -> GDN1 (MFMA)
//   -> conv2 5x5s2 (MFMA polyphase) -> GDN2 (MFMA) -> conv3 3x3 (MFMA, bf16)
//   -> attn_mega (32-row q tiles, grid 512 -> 2 blocks/CU): LN(q)+LN(kv) ->
//      QKV proj -> Bahdanau attention -> outproj + residual + LN + transpose.
// 7 launches.
// ---------------------------------------------------------------------------

typedef __bf16 bf16x8 __attribute__((ext_vector_type(8)));
typedef float floatx4 __attribute__((ext_vector_type(4)));
typedef unsigned short ushortT;
typedef unsigned short ushort8v __attribute__((ext_vector_type(8)));

#if __has_builtin(__builtin_amdgcn_exp2f)
#define EXP2F(x) __builtin_amdgcn_exp2f(x)
#else
#define EXP2F(x) exp2f(x)
#endif
#if __has_builtin(__builtin_amdgcn_rcpf)
#define RCPF(x) __builtin_amdgcn_rcpf(x)
#else
#define RCPF(x) (1.f / (x))
#endif

__device__ __forceinline__ ushortT f2bf(float f) {
  unsigned u = __builtin_bit_cast(unsigned, f);
  unsigned r = (u + 0x7FFFu + ((u >> 16) & 1u)) >> 16;
  return (ushortT)r;
}
__device__ __forceinline__ float bf2f(ushortT u) {
  return __builtin_bit_cast(float, ((unsigned)u) << 16);
}

// ---- workspace layout (float-slot offsets) ----
static constexpr size_t OFF_T1BF = 0;          // conv1 out bf16 (64,1024,128)
static constexpr size_t OFF_X2BF = 4194304;    // gdn1 out bf16 [b][4][256][128]
static constexpr size_t OFF_T2BF = 8388608;    // conv2 out bf16 (64,256,128)
static constexpr size_t OFF_X3BF = 9437184;    // gdn2 out bf16 (64,256,128)
static constexpr size_t OFF_QRAW = 10485760;   // conv3 out bf16 (64,256,192)
static constexpr size_t OFF_WBQ  = 21299200;   // bf16 128x192 (scaled by c)
static constexpr size_t OFF_WBK  = 21311488;   // bf16 128x192 (scaled by c)
static constexpr size_t OFF_WBV  = 21323776;   // bf16 192x192
static constexpr size_t OFF_WBO  = 21342208;   // bf16 192x192
static constexpr size_t OFF_WT2  = 26079232;   // bf16 conv2 slabs [200][2048]
static constexpr size_t OFF_WT3  = 26284032;   // bf16 conv3 slabs [108][2048]
static constexpr size_t OFF_WC1  = 26394624;   // bf16 conv1 slabs [5][128][32]
static constexpr size_t OFF_GB1  = 26406912;   // bf16 gamma1 128x128
static constexpr size_t OFF_GB2  = 26415104;   // bf16 gamma2 128x128

// 5x5 s2 p2 polyphase tap tables (tap id = kh*5+kw); HW-verified via conv2.
__device__ __constant__ int d_TWI2[4][9] = {{ 0, 2, 4,10,12,14,20,22,24},
                                            { 1, 3,11,13,21,23, 0, 0, 0},
                                            { 5, 7, 9,15,17,19, 0, 0, 0},
                                            { 6, 8,16,18, 0, 0, 0, 0, 0}};
__device__ __constant__ int d_NT2[4] = {9, 6, 6, 4};

// ---------------------------------------------------------------------------
// fused prep: all weight repacks/casts in one launch, block-range dispatch.
// ---------------------------------------------------------------------------
__device__ void dev_convw3(const float* w, ushortT* wt, int mode, int total,
                           int idx) {
  if (idx >= total) return;
  int j    = idx & 7;
  int om   = (idx >> 3) & 63;
  int kg   = (idx >> 9) & 3;
  int slab = idx >> 11;
  int mt, s, tap, T;
  if (mode == 0) {
    int ph;
    if (slab < 72) ph = 0; else if (slab < 120) ph = 1;
    else if (slab < 168) ph = 2; else ph = 3;
    const int st[4] = {0, 72, 120, 168};
    const int ns[4] = {36, 24, 24, 16};
    int rel = slab - st[ph];
    mt = rel / ns[ph]; s = rel % ns[ph];
    tap = d_TWI2[ph][s >> 2]; T = 25;
  } else {
    mt = slab / 36; s = slab % 36; tap = s >> 2; T = 9;
  }
  int cc = s & 3;
  int c  = cc * 32 + kg * 8 + j;
  int oc = mt * 64 + om;
  wt[idx] = f2bf(w[(size_t)(oc * 128 + c) * T + tap]);
}

__device__ void dev_convw1(const float* w, ushortT* wt, int idx) {
  if (idx >= 20480) return;
  int k    = idx & 31;
  int oc   = (idx >> 5) & 127;
  int slab = idx >> 12;
  int ph, i;
  if (slab < 2) { ph = 0; i = slab; } else { ph = slab - 1; i = 0; }
  int kg = k >> 3, jj = k & 7;
  int tidx = i * 8 + jj;
  float val = 0.f;
  if (kg < 3 && tidx < d_NT2[ph]) {
    int tap = d_TWI2[ph][tidx];
    val = w[(size_t)(oc * 3 + kg) * 25 + tap];
  }
  wt[idx] = f2bf(val);
}

__device__ void dev_wcast(const float* w, ushortT* wb, int total, float scale,
                          int idx) {
  if (idx < total) wb[idx] = f2bf(w[idx] * scale);
}

__global__ __launch_bounds__(256) void prep_kernel(
    const float* __restrict__ conv2_w, ushortT* __restrict__ wt2,
    const float* __restrict__ conv3_w, ushortT* __restrict__ wt3,
    const float* __restrict__ conv1_w, ushortT* __restrict__ wc1,
    const float* __restrict__ Wq, ushortT* __restrict__ wbq,
    const float* __restrict__ Wk, ushortT* __restrict__ wbk,
    const float* __restrict__ Wv, ushortT* __restrict__ wbv,
    const float* __restrict__ out_w, ushortT* __restrict__ wbo,
    const float* __restrict__ gamma1, ushortT* __restrict__ gb1,
    const float* __restrict__ gamma2, ushortT* __restrict__ gb2) {
  constexpr float C2LE = 2.88539008177792681f;   // 2*log2(e)
  int blk = blockIdx.x, tid = threadIdx.x;
  if (blk < 1600)      dev_convw3(conv2_w, wt2, 0, 409600, blk * 256 + tid);
  else if (blk < 2464) dev_convw3(conv3_w, wt3, 1, 221184, (blk - 1600) * 256 + tid);
  else if (blk < 2544) dev_convw1(conv1_w, wc1, (blk - 2464) * 256 + tid);
  else if (blk < 2640) dev_wcast(Wq, wbq, 24576, C2LE, (blk - 2544) * 256 + tid);
  else if (blk < 2736) dev_wcast(Wk, wbk, 24576, C2LE, (blk - 2640) * 256 + tid);
  else if (blk < 2880) dev_wcast(Wv, wbv, 36864, 1.f, (blk - 2736) * 256 + tid);
  else if (blk < 3024) dev_wcast(out_w, wbo, 36864, 1.f, (blk - 2880) * 256 + tid);
  else if (blk < 3088) dev_wcast(gamma1, gb1, 16384, 1.f, (blk - 3024) * 256 + tid);
  else                 dev_wcast(gamma2, gb2, 16384, 1.f, (blk - 3088) * 256 + tid);
}

// ---------------------------------------------------------------------------
// conv1 MFMA polyphase: (64,3,64,64) fp32 -> (64,1024px,128c) bf16.
// ---------------------------------------------------------------------------
__global__ __launch_bounds__(256, 1) void conv1_mfma_kernel(
    const float* __restrict__ x, const ushortT* __restrict__ wc1,
    const float* __restrict__ bias, ushortT* __restrict__ outb) {
  int b  = blockIdx.x >> 2;
  int yg = blockIdx.x & 3;
  int y0 = yg * 8;

  int wave = threadIdx.x >> 6;
  int lane = threadIdx.x & 63;
  int ln15 = lane & 15;
  int kg   = lane >> 4;
  int tid  = threadIdx.x;

  __shared__ ushortT simg[4680];
  __shared__ ushortT sA[5 * 128 * 40];

  for (int j = tid; j < 2340; j += 256) ((unsigned*)simg)[j] = 0u;
  __syncthreads();

  int ihBase = 2 * y0 - 2;
  const float* xb = x + (size_t)b * 3 * 4096;
  for (int j = tid; j < 960; j += 256) {
    int q = j & 15;
    int rr = j >> 4;
    int c = rr / 20, ihl = rr % 20;
    int ih = ihBase + ihl;
    if (ih >= 0 && ih < 64) {
      float4 v = *(const float4*)&xb[c * 4096 + ih * 64 + q * 4];
      int pr = ih & 1, u = ih >> 1;
      int lr = u - y0 + 1;
      int base0 = ((pr * 2 + 0) * 3 + c) * 360 + lr * 36;
      int base1 = ((pr * 2 + 1) * 3 + c) * 360 + lr * 36;
      simg[base0 + 2 * q + 1] = f2bf(v.x);
      simg[base1 + 2 * q + 1] = f2bf(v.y);
      simg[base0 + 2 * q + 2] = f2bf(v.z);
      simg[base1 + 2 * q + 2] = f2bf(v.w);
    }
  }
  for (int j = tid; j < 2560; j += 256) {
    int chunk = j & 3, row = j >> 2;
    uint4 v = *(const uint4*)&wc1[row * 32 + chunk * 8];
    *(uint4*)&sA[row * 40 + chunk * 8] = v;
  }
  __syncthreads();

  constexpr int TDR[4][9] = {{-1,-1,-1, 0, 0, 0, 1, 1, 1},
                             {-1,-1, 0, 0, 1, 1, 0, 0, 0},
                             {-1,-1,-1, 0, 0, 0, 0, 0, 0},
                             {-1,-1, 0, 0, 0, 0, 0, 0, 0}};
  constexpr int TDC[4][9] = {{-1, 0, 1,-1, 0, 1,-1, 0, 1},
                             {-1, 0,-1, 0,-1, 0, 0, 0, 0},
                             {-1, 0, 1,-1, 0, 1, 0, 0, 0},
                             {-1, 0,-1, 0, 0, 0, 0, 0, 0}};
  constexpr int NT[4]  = {9, 6, 6, 4};
  constexpr int NM[4]  = {2, 1, 1, 1};
  constexpr int SB[4]  = {0, 2, 3, 4};

  ushort8v Bf[4][5];
  #pragma unroll
  for (int ntl = 0; ntl < 4; ++ntl) {
    int ntg = wave * 4 + ntl;
    int yloc = ntg >> 1;
    int xx = (ntg & 1) * 16 + ln15;
    int lbase = (yloc + 1) * 36 + xx + 1 + kg * 360;
    #pragma unroll
    for (int ph = 0; ph < 4; ++ph) {
      int pbase = ph * 1080 + lbase;
      #pragma unroll
      for (int i = 0; i < 2; ++i) {
        if (i < NM[ph]) {
          ushort8v bv;
          #pragma unroll
          for (int j = 0; j < 8; ++j) {
            int tidx = i * 8 + j;
            if (tidx >= NT[ph]) tidx = 0;
            int off = TDR[ph][tidx] * 36 + TDC[ph][tidx];
            bv[j] = simg[pbase + off];
          }
          Bf[ntl][SB[ph] + i] = bv;
        }
      }
    }
  }

  #pragma unroll
  for (int m = 0; m < 8; ++m) {
    bf16x8 Af[5];
    #pragma unroll
    for (int s = 0; s < 5; ++s)
      Af[s] = *(const bf16x8*)&sA[(s * 128 + m * 16 + ln15) * 40 + kg * 8];
    int oc0 = m * 16 + kg * 4;
    float4 bv = *(const float4*)&bias[oc0];
    #pragma unroll
    for (int ntl = 0; ntl < 4; ++ntl) {
      floatx4 acc = (floatx4)0.f;
      #pragma unroll
      for (int s = 0; s < 5; ++s)
        acc = __builtin_amdgcn_mfma_f32_16x16x32_bf16(
            Af[s], __builtin_bit_cast(bf16x8, Bf[ntl][s]), acc, 0, 0, 0);
      int ntg = wave * 4 + ntl;
      int y = y0 + (ntg >> 1);
      int xx = (ntg & 1) * 16 + ln15;
      int p = y * 32 + xx;
      ushort4 o4 = {f2bf(acc[0] + bv.x), f2bf(acc[1] + bv.y),
                    f2bf(acc[2] + bv.z), f2bf(acc[3] + bv.w)};
      *(ushort4*)&outb[((size_t)b * 1024 + p) * 128 + oc0] = o4;
    }
  }
}

// ---------------------------------------------------------------------------
// GDN as bf16 MFMA GEMM.
// ---------------------------------------------------------------------------
__global__ __launch_bounds__(256) void gdn_mfma_kernel(
    const ushortT* __restrict__ xbf, const ushortT* __restrict__ gb,
    const float* __restrict__ beta, ushortT* __restrict__ ybf,
    int HW, int nPixTiles, int isSplit) {
  int pt = blockIdx.x % nPixTiles;
  int b  = blockIdx.x / nPixTiles;
  int px0 = pt * 64;
  int tid = threadIdx.x;
  int wave = tid >> 6, lane = tid & 63, ln15 = lane & 15, kg = lane >> 4;

  __shared__ ushortT sG[128 * 136];
  __shared__ ushortT sX[64 * 136];

  for (int j = tid; j < 2048; j += 256) {
    int row = j >> 4, ch = j & 15;
    *(uint4*)&sG[row * 136 + ch * 8] = *(const uint4*)&gb[row * 128 + ch * 8];
  }
  for (int j = tid; j < 1024; j += 256) {
    int row = j >> 4, ch = j & 15;
    ushort8v xv = *(const ushort8v*)&xbf[((size_t)(b * HW + px0 + row)) * 128 + ch * 8];
    ushort8v sq;
    #pragma unroll
    for (int r = 0; r < 8; ++r) {
      float f = bf2f(xv[r]);
      sq[r] = f2bf(f * f);
    }
    *(ushort8v*)&sX[row * 136 + ch * 8] = sq;
  }
  __syncthreads();

  floatx4 acc[2][4];
  #pragma unroll
  for (int mi = 0; mi < 2; ++mi)
    #pragma unroll
    for (int nt = 0; nt < 4; ++nt) acc[mi][nt] = (floatx4)0.f;

  #pragma unroll
  for (int k0 = 0; k0 < 128; k0 += 32) {
    bf16x8 a0 = *(const bf16x8*)&sG[(wave * 32 + ln15) * 136 + k0 + kg * 8];
    bf16x8 a1 = *(const bf16x8*)&sG[(wave * 32 + 16 + ln15) * 136 + k0 + kg * 8];
    #pragma unroll
    for (int nt = 0; nt < 4; ++nt) {
      bf16x8 bb = *(const bf16x8*)&sX[(nt * 16 + ln15) * 136 + k0 + kg * 8];
      acc[0][nt] = __builtin_amdgcn_mfma_f32_16x16x32_bf16(a0, bb, acc[0][nt], 0, 0, 0);
      acc[1][nt] = __builtin_amdgcn_mfma_f32_16x16x32_bf16(a1, bb, acc[1][nt], 0, 0, 0);
    }
  }

  #pragma unroll
  for (int mi = 0; mi < 2; ++mi) {
    int d0 = wave * 32 + mi * 16 + kg * 4;
    float4 bt = *(const float4*)&beta[d0];
    #pragma unroll
    for (int nt = 0; nt < 4; ++nt) {
      int p = px0 + nt * 16 + ln15;
      ushort4 x4 = *(const ushort4*)&xbf[((size_t)(b * HW + p)) * 128 + d0];
      ushort4 o4;
      o4.x = f2bf(bf2f(x4.x) * rsqrtf(acc[mi][nt][0] + bt.x));
      o4.y = f2bf(bf2f(x4.y) * rsqrtf(acc[mi][nt][1] + bt.y));
      o4.z = f2bf(bf2f(x4.z) * rsqrtf(acc[mi][nt][2] + bt.z));
      o4.w = f2bf(bf2f(x4.w) * rsqrtf(acc[mi][nt][3] + bt.w));
      size_t dst;
      if (isSplit) {
        int h = p >> 5, w5 = p & 31;
        int ph = ((h & 1) << 1) | (w5 & 1);
        dst = (((size_t)b * 4 + ph) * 256 + (h >> 1) * 16 + (w5 >> 1)) * 128 + d0;
      } else {
        dst = ((size_t)b * 256 + p) * 128 + d0;
      }
      *(ushort4*)&ybf[dst] = o4;
    }
  }
}

// ---------------------------------------------------------------------------
// conv2/conv3 MFMA implicit GEMM; 4-row split, 2 blocks/CU, bf16 out.
// ---------------------------------------------------------------------------
template<int MODE>
__global__ __launch_bounds__(256, 2) void conv_mfma_kernel(
    const ushortT* __restrict__ X,
    const ushortT* __restrict__ Wt,
    const float* __restrict__ bias,
    ushortT* __restrict__ outb) {
  constexpr int OC  = (MODE == 0) ? 128 : 192;
  constexpr int NMT = OC / 64;
  constexpr int NPH = (MODE == 0) ? 4 : 1;

  int b   = blockIdx.x / (NMT * 4);
  int rem = blockIdx.x % (NMT * 4);
  int mt  = rem >> 2;
  int rs  = rem & 3;
  int r0  = rs * 4;

  int wave = threadIdx.x >> 6;
  int lane = threadIdx.x & 63;
  int ln15 = lane & 15;
  int kg   = lane >> 4;

  __shared__ ushortT simg[6 * 18 * 136];

  floatx4 acc[4];
  #pragma unroll
  for (int m = 0; m < 4; ++m) acc[m] = (floatx4)0.f;

  constexpr int NS2[4]      = {36, 24, 24, 16};
  constexpr int PHSTART2[4] = {0, 72, 120, 168};
  constexpr int TDR_2[4][9] = {{-1,-1,-1, 0, 0, 0, 1, 1, 1},
                               {-1,-1, 0, 0, 1, 1, 0, 0, 0},
                               {-1,-1,-1, 0, 0, 0, 0, 0, 0},
                               {-1,-1, 0, 0, 0, 0, 0, 0, 0}};
  constexpr int TDC_2[4][9] = {{-1, 0, 1,-1, 0, 1,-1, 0, 1},
                               {-1, 0,-1, 0,-1, 0, 0, 0, 0},
                               {-1, 0, 1,-1, 0, 1, 0, 0, 0},
                               {-1, 0,-1, 0, 0, 0, 0, 0, 0}};
  constexpr int TDR_3[9] = {-1,-1,-1, 0, 0, 0, 1, 1, 1};
  constexpr int TDC_3[9] = {-1, 0, 1,-1, 0, 1,-1, 0, 1};

  const int aoff = kg * 512 + ln15 * 8;
  uint4 apf[8][4];

  #pragma unroll
  for (int ph = 0; ph < NPH; ++ph) {
    const int NS = (MODE == 0) ? NS2[ph] : 36;
    const int slabBase = (MODE == 0) ? (PHSTART2[ph] + mt * NS2[ph]) : (mt * 36);
    const ushortT* wp0 = Wt + (size_t)slabBase * 2048 + aoff;

    __syncthreads();
    const ushortT* Xb = X + (((size_t)b * NPH + ph) * 256) * 128;
    for (int idx = threadIdx.x; idx < 1728; idx += 256) {
      int chunk = idx & 15;
      int pix = idx >> 4;
      int row = pix / 18, colm = pix - row * 18;
      int i = r0 - 1 + row, j = colm - 1;
      uint4 v = {0u, 0u, 0u, 0u};
      if (i >= 0 && i < 16 && j >= 0 && j < 16)
        v = *(const uint4*)(Xb + ((size_t)(i * 16 + j)) * 128 + chunk * 8);
      *(uint4*)&simg[(row * 18 + colm) * 136 + chunk * 8] = v;
    }
    #pragma unroll
    for (int jj = 0; jj < 8; ++jj)
      if (jj < NS) {
        #pragma unroll
        for (int m = 0; m < 4; ++m)
          apf[jj][m] = *(const uint4*)(wp0 + (size_t)jj * 2048 + m * 128);
      }
    __syncthreads();

    #pragma unroll
    for (int s0 = 0; s0 < NS; s0 += 8) {
      #pragma unroll
      for (int jj = 0; jj < 8; ++jj) {
        int s = s0 + jj;
        if (s < NS) {
          bf16x8 acur[4];
          #pragma unroll
          for (int m = 0; m < 4; ++m) acur[m] = __builtin_bit_cast(bf16x8, apf[jj][m]);
          int sp = s + 8;
          if (sp < NS) {
            #pragma unroll
            for (int m = 0; m < 4; ++m)
              apf[jj][m] = *(const uint4*)(wp0 + (size_t)sp * 2048 + m * 128);
          }
          int t  = s >> 2;
          int c0 = (s & 3) * 32;
          int dr = (MODE == 0) ? TDR_2[ph][t] : TDR_3[t];
          int dc = (MODE == 0) ? TDC_2[ph][t] : TDC_3[t];
          int lrow = wave + dr + 1;
          int lcol = ln15 + dc + 1;
          bf16x8 bfr = *(const bf16x8*)&simg[(lrow * 18 + lcol) * 136 + c0 + kg * 8];
          #pragma unroll
          for (int m = 0; m < 4; ++m)
            acc[m] = __builtin_amdgcn_mfma_f32_16x16x32_bf16(acur[m], bfr, acc[m], 0, 0, 0);
        }
      }
    }
  }

  #pragma unroll
  for (int m = 0; m < 4; ++m) {
    int mg = mt * 64 + m * 16 + kg * 4;
    float4 bv = *(const float4*)&bias[mg];
    int r = r0 + wave;
    int p = r * 16 + ln15;
    ushort4 o4 = {f2bf(acc[m][0] + bv.x), f2bf(acc[m][1] + bv.y),
                  f2bf(acc[m][2] + bv.z), f2bf(acc[m][3] + bv.w)};
    *(ushort4*)&outb[((size_t)b * 256 + p) * OC + mg] = o4;
  }
}

// ---------------------------------------------------------------------------
// attn_mega v2: 32-row q tiles, grid 512 (b x 8), ~42.5KB LDS -> 2+ blocks/CU.
// Phase-overlaid LDS (ushort offsets):
//   QLN  [0,6400)        bf16 [32][200]  ph1-2
//   KV   [6400,12800)    bf16 [32][200]  ph1-2b
//   QP   [12800,17152)   bf16 [32][136]  ph2-3
//   KP   [17152,21504)   bf16 [32][136]  ph2-3
//   SWM  [21504,21760)   f32  [128]      ph2b-3
//   S0   [21760,21762)   f32
//   VP   [0,6400)        bf16 [32][200]  ph2b-5 (over dead QLN)
//   SE   [6400,8512)     f32  [32][33]   ph3-5  (over dead KV head)
//   CTX  [12800,19200)   bf16 [32][200]  ph5-6  (over dead QP/KP)
//   SF   [0,12352)       f32  [32][193]  ph6    (over dead VP/SE)
// ---------------------------------------------------------------------------
__global__ __launch_bounds__(256) void attn_mega_kernel(
    const ushortT* __restrict__ qrawb, const float* __restrict__ ln_q_w,
    const float* __restrict__ ln_q_b, const float* __restrict__ yg,
    const float* __restrict__ ln_kv_w, const float* __restrict__ ln_kv_b,
    const ushortT* __restrict__ wbq, const ushortT* __restrict__ wbk,
    const ushortT* __restrict__ wbv, const ushortT* __restrict__ wbo,
    const float* __restrict__ vw, const float* __restrict__ out_b,
    const float* __restrict__ ln_out_w, const float* __restrict__ ln_out_b,
    float* __restrict__ out) {
  __shared__ ushortT smem[21762];
  ushortT* sqln = smem;
  ushortT* skv  = smem + 6400;
  ushortT* sqp  = smem + 12800;
  ushortT* skp  = smem + 17152;
  float*   swm  = (float*)(smem + 21504);
  float*   sS0  = (float*)(smem + 21760);
  ushortT* svp  = smem;
  float*   se   = (float*)(smem + 6400);
  ushortT* sctx = smem + 12800;
  float*   sf   = (float*)smem;

  int b  = blockIdx.x >> 3;
  int t0 = (blockIdx.x & 7) * 32;
  int tid  = threadIdx.x;
  int wave = tid >> 6;
  int lane = tid & 63;
  int ln15 = lane & 15;
  int kg   = lane >> 4;

  // ---- ph1: LN(q rows) -> sqln; LN(kv gather) -> skv ----
  for (int r = wave; r < 32; r += 4) {
    const ushortT* xr = qrawb + ((size_t)(b * 256 + t0 + r)) * 192;
    float v0 = bf2f(xr[lane]), v1 = bf2f(xr[lane + 64]), v2 = bf2f(xr[lane + 128]);
    float s = v0 + v1 + v2;
    float s2 = v0 * v0 + v1 * v1 + v2 * v2;
    #pragma unroll
    for (int off = 32; off; off >>= 1) { s += __shfl_xor(s, off); s2 += __shfl_xor(s2, off); }
    float mean = s * (1.f / 192.f);
    float var = s2 * (1.f / 192.f) - mean * mean;
    float inv = rsqrtf(var + 1e-5f);
    sqln[r * 200 + lane]       = f2bf((v0 - mean) * inv * ln_q_w[lane]       + ln_q_b[lane]);
    sqln[r * 200 + lane + 64]  = f2bf((v1 - mean) * inv * ln_q_w[lane + 64]  + ln_q_b[lane + 64]);
    sqln[r * 200 + lane + 128] = f2bf((v2 - mean) * inv * ln_q_w[lane + 128] + ln_q_b[lane + 128]);
  }
  for (int r = wave; r < 32; r += 4) {
    const float* src = yg + (size_t)b * 6144 + r;
    float v0 = src[(size_t)lane * 32];
    float v1 = src[(size_t)(lane + 64) * 32];
    float v2 = src[(size_t)(lane + 128) * 32];
    float s = v0 + v1 + v2;
    float s2 = v0 * v0 + v1 * v1 + v2 * v2;
    #pragma unroll
    for (int off = 32; off; off >>= 1) { s += __shfl_xor(s, off); s2 += __shfl_xor(s2, off); }
    float mean = s * (1.f / 192.f);
    float var = s2 * (1.f / 192.f) - mean * mean;
    float inv = rsqrtf(var + 1e-5f);
    skv[r * 200 + lane]       = f2bf((v0 - mean) * inv * ln_kv_w[lane]       + ln_kv_b[lane]);
    skv[r * 200 + lane + 64]  = f2bf((v1 - mean) * inv * ln_kv_w[lane + 64]  + ln_kv_b[lane + 64]);
    skv[r * 200 + lane + 128] = f2bf((v2 - mean) * inv * ln_kv_w[lane + 128] + ln_kv_b[lane + 128]);
  }
  __syncthreads();

  // ---- ph2: qproj (sqln x wbq -> sqp), kproj (skv x wbk -> skp) ----
  for (int ti = wave; ti < 16; ti += 4) {       // qproj: 2 rt x 8 ct
    int rt = ti >> 3, ct = ti & 7;
    floatx4 acc = (floatx4)0.f;
    #pragma unroll
    for (int k0 = 0; k0 < 192; k0 += 32) {
      bf16x8 afr = *(const bf16x8*)&sqln[(rt * 16 + ln15) * 200 + k0 + kg * 8];
      bf16x8 bfr = *(const bf16x8*)&wbq[((size_t)(ct * 16 + ln15)) * 192 + k0 + kg * 8];
      acc = __builtin_amdgcn_mfma_f32_16x16x32_bf16(afr, bfr, acc, 0, 0, 0);
    }
    #pragma unroll
    for (int r = 0; r < 4; ++r)
      sqp[(rt * 16 + kg * 4 + r) * 136 + ct * 16 + ln15] = f2bf(acc[r]);
  }
  for (int ti = wave; ti < 16; ti += 4) {       // kproj: 2 rt x 8 ct
    int rt = ti >> 3, ct = ti & 7;
    floatx4 acc = (floatx4)0.f;
    #pragma unroll
    for (int k0 = 0; k0 < 192; k0 += 32) {
      bf16x8 afr = *(const bf16x8*)&skv[(rt * 16 + ln15) * 200 + k0 + kg * 8];
      bf16x8 bfr = *(const bf16x8*)&wbk[((size_t)(ct * 16 + ln15)) * 192 + k0 + kg * 8];
      acc = __builtin_amdgcn_mfma_f32_16x16x32_bf16(afr, bfr, acc, 0, 0, 0);
    }
    #pragma unroll
    for (int r = 0; r < 4; ++r)
      skp[(rt * 16 + kg * 4 + r) * 136 + ct * 16 + ln15] = f2bf(acc[r]);
  }
  __syncthreads();

  // ---- ph2b: vproj (skv x wbv -> svp, over dead sqln) + swm/S0 ----
  for (int ti = wave; ti < 24; ti += 4) {       // 2 rt x 12 ct
    int rt = ti / 12, ct = ti % 12;
    floatx4 acc = (floatx4)0.f;
    #pragma unroll
    for (int k0 = 0; k0 < 192; k0 += 32) {
      bf16x8 afr = *(const bf16x8*)&skv[(rt * 16 + ln15) * 200 + k0 + kg * 8];
      bf16x8 bfr = *(const bf16x8*)&wbv[((size_t)(ct * 16 + ln15)) * 192 + k0 + kg * 8];
      acc = __builtin_amdgcn_mfma_f32_16x16x32_bf16(afr, bfr, acc, 0, 0, 0);
    }
    #pragma unroll
    for (int r = 0; r < 4; ++r)
      svp[(rt * 16 + kg * 4 + r) * 200 + ct * 16 + ln15] = f2bf(acc[r]);
  }
  if (tid < 128) swm[tid] = -2.f * vw[tid];
  if (tid < 64) {
    float s = vw[tid] + vw[tid + 64];
    #pragma unroll
    for (int off = 32; off; off >>= 1) s += __shfl_xor(s, off);
    if (tid == 0) *sS0 = s;
  }
  __syncthreads();

  // ---- ph3: energy -> se ----
  {
    float S0v = *sS0;
    int qq0 = tid >> 4, kc = tid & 15;
    const float4* w4 = (const float4*)swm;
    #pragma unroll
    for (int st = 0; st < 2; ++st) {
      int qq = st * 16 + qq0;
      const ushortT* qrow = sqp + qq * 136;
      const ushortT* kr0 = skp + kc * 136;
      const ushortT* kr1 = skp + (kc + 16) * 136;
      float acc0 = S0v, acc1 = S0v;
      #pragma unroll 8
      for (int d4 = 0; d4 < 32; ++d4) {
        ushort4 qu = *(const ushort4*)&qrow[d4 * 4];
        ushort4 k0u = *(const ushort4*)&kr0[d4 * 4];
        ushort4 k1u = *(const ushort4*)&kr1[d4 * 4];
        float4 wv = w4[d4];
        float qx = bf2f(qu.x), qy = bf2f(qu.y), qz = bf2f(qu.z), qw = bf2f(qu.w);
        acc0 += wv.x * RCPF(EXP2F(qx + bf2f(k0u.x)) + 1.f);
        acc0 += wv.y * RCPF(EXP2F(qy + bf2f(k0u.y)) + 1.f);
        acc0 += wv.z * RCPF(EXP2F(qz + bf2f(k0u.z)) + 1.f);
        acc0 += wv.w * RCPF(EXP2F(qw + bf2f(k0u.w)) + 1.f);
        acc1 += wv.x * RCPF(EXP2F(qx + bf2f(k1u.x)) + 1.f);
        acc1 += wv.y * RCPF(EXP2F(qy + bf2f(k1u.y)) + 1.f);
        acc1 += wv.z * RCPF(EXP2F(qz + bf2f(k1u.z)) + 1.f);
        acc1 += wv.w * RCPF(EXP2F(qw + bf2f(k1u.w)) + 1.f);
      }
      se[qq * 33 + kc] = acc0;
      se[qq * 33 + kc + 16] = acc1;
    }
  }
  __syncthreads();

  // ---- ph4: softmax rows ----
  if (tid < 32) {
    float* ser = se + tid * 33;
    float mx = -1e30f;
    for (int k = 0; k < 32; ++k) mx = fmaxf(mx, ser[k]);
    float s = 0.f;
    for (int k = 0; k < 32; ++k) { float a = __expf(ser[k] - mx); ser[k] = a; s += a; }
    float invs = 1.f / s;
    for (int k = 0; k < 32; ++k) ser[k] *= invs;
  }
  __syncthreads();

  // ---- ph5: PV -> sctx (over dead sqp/skp) ----
  for (int j = tid; j < 1536; j += 256) {
    int qq = j / 48, m4 = j % 48;
    const float* al = se + qq * 33;
    float4 a = {0.f, 0.f, 0.f, 0.f};
    #pragma unroll 8
    for (int k = 0; k < 32; ++k) {
      float wk = al[k];
      ushort4 vv = *(const ushort4*)&svp[k * 200 + m4 * 4];
      a.x += wk * bf2f(vv.x); a.y += wk * bf2f(vv.y);
      a.z += wk * bf2f(vv.z); a.w += wk * bf2f(vv.w);
    }
    ushort4 o4 = {f2bf(a.x), f2bf(a.y), f2bf(a.z), f2bf(a.w)};
    *(ushort4*)&sctx[qq * 200 + m4 * 4] = o4;
  }
  __syncthreads();

  // ---- ph6: outproj -> sf; residual(re-LN)+final LN; transpose store ----
  for (int ti = wave; ti < 24; ti += 4) {       // 2 rt x 12 ct
    int rt = ti / 12, ct = ti % 12;
    floatx4 acc = (floatx4)0.f;
    #pragma unroll
    for (int k0 = 0; k0 < 192; k0 += 32) {
      bf16x8 afr = *(const bf16x8*)&sctx[(rt * 16 + ln15) * 200 + k0 + kg * 8];
      bf16x8 bfr = *(const bf16x8*)&wbo[((size_t)(ct * 16 + ln15)) * 192 + k0 + kg * 8];
      acc = __builtin_amdgcn_mfma_f32_16x16x32_bf16(afr, bfr, acc, 0, 0, 0);
    }
    float bv = out_b[ct * 16 + ln15];
    #pragma unroll
    for (int r = 0; r < 4; ++r)
      sf[(rt * 16 + kg * 4 + r) * 193 + ct * 16 + ln15] = acc[r] + bv;
  }
  __syncthreads();

  for (int rr = wave; rr < 32; rr += 4) {
    int t = t0 + rr;
    const ushortT* xr = qrawb + ((size_t)(b * 256 + t)) * 192;
    float r0_ = bf2f(xr[lane]), r1_ = bf2f(xr[lane + 64]), r2_ = bf2f(xr[lane + 128]);
    float s = r0_ + r1_ + r2_;
    float s2 = r0_ * r0_ + r1_ * r1_ + r2_ * r2_;
    #pragma unroll
    for (int off = 32; off; off >>= 1) { s += __shfl_xor(s, off); s2 += __shfl_xor(s2, off); }
    float mean = s * (1.f / 192.f);
    float var = s2 * (1.f / 192.f) - mean * mean;
    float inv = rsqrtf(var + 1e-5f);
    float q0 = (r0_ - mean) * inv * ln_q_w[lane]       + ln_q_b[lane];
    float q1 = (r1_ - mean) * inv * ln_q_w[lane + 64]  + ln_q_b[lane + 64];
    float q2 = (r2_ - mean) * inv * ln_q_w[lane + 128] + ln_q_b[lane + 128];
    float v0 = sf[rr * 193 + lane]       + q0;
    float v1 = sf[rr * 193 + lane + 64]  + q1;
    float v2 = sf[rr * 193 + lane + 128] + q2;
    float t_s = v0 + v1 + v2;
    float t_s2 = v0 * v0 + v1 * v1 + v2 * v2;
    #pragma unroll
    for (int off = 32; off; off >>= 1) { t_s += __shfl_xor(t_s, off); t_s2 += __shfl_xor(t_s2, off); }
    float m2 = t_s * (1.f / 192.f);
    float var2 = t_s2 * (1.f / 192.f) - m2 * m2;
    float inv2 = rsqrtf(var2 + 1e-5f);
    sf[rr * 193 + lane]       = (v0 - m2) * inv2 * ln_out_w[lane]       + ln_out_b[lane];
    sf[rr * 193 + lane + 64]  = (v1 - m2) * inv2 * ln_out_w[lane + 64]  + ln_out_b[lane + 64];
    sf[rr * 193 + lane + 128] = (v2 - m2) * inv2 * ln_out_w[lane + 128] + ln_out_b[lane + 128];
  }
  __syncthreads();

  for (int j = tid; j < 1536; j += 256) {
    int m = j >> 3, t4 = j & 7;
    float4 o4;
    o4.x = sf[(t4 * 4 + 0) * 193 + m];
    o4.y = sf[(t4 * 4 + 1) * 193 + m];
    o4.z = sf[(t4 * 4 + 2) * 193 + m];
    o4.w = sf[(t4 * 4 + 3) * 193 + m];
    *(float4*)&out[((size_t)(b * 192 + m)) * 256 + t0 + t4 * 4] = o4;
  }
}

// ---------------------------------------------------------------------------
extern "C" void kernel_launch(void* const* d_in, const int* in_sizes, int n_in,
                              void* d_out, int out_size, void* d_ws, size_t ws_size,
                              hipStream_t stream) {
  (void)in_sizes; (void)n_in; (void)out_size; (void)ws_size;
  const float* x_p     = (const float*)d_in[0];
  const float* y_g     = (const float*)d_in[1];
  const float* conv1_w = (const float*)d_in[2];
  const float* conv1_b = (const float*)d_in[3];
  const float* gamma1  = (const float*)d_in[4];
  const float* beta1   = (const float*)d_in[5];
  const float* conv2_w = (const float*)d_in[6];
  const float* conv2_b = (const float*)d_in[7];
  const float* gamma2  = (const float*)d_in[8];
  const float* beta2   = (const float*)d_in[9];
  const float* conv3_w = (const float*)d_in[10];
  const float* conv3_b = (const float*)d_in[11];
  const float* ln_q_w  = (const float*)d_in[12];
  const float* ln_q_b  = (const float*)d_in[13];
  const float* ln_kv_w = (const float*)d_in[14];
  const float* ln_kv_b = (const float*)d_in[15];
  const float* ln_out_w= (const float*)d_in[16];
  const float* ln_out_b= (const float*)d_in[17];
  const float* Wq      = (const float*)d_in[18];
  const float* Wk      = (const float*)d_in[19];
  const float* v_w     = (const float*)d_in[20];
  const float* Wv      = (const float*)d_in[21];
  const float* out_w   = (const float*)d_in[22];
  const float* out_b   = (const float*)d_in[23];
  float* out = (float*)d_out;
  float* ws  = (float*)d_ws;

  ushortT* t1bf  = (ushortT*)(ws + OFF_T1BF);
  ushortT* x2bf  = (ushortT*)(ws + OFF_X2BF);
  ushortT* t2bf  = (ushortT*)(ws + OFF_T2BF);
  ushortT* x3bf  = (ushortT*)(ws + OFF_X3BF);
  ushortT* qrawb = (ushortT*)(ws + OFF_QRAW);
  ushortT* wbq   = (ushortT*)(ws + OFF_WBQ);
  ushortT* wbk   = (ushortT*)(ws + OFF_WBK);
  ushortT* wbv   = (ushortT*)(ws + OFF_WBV);
  ushortT* wbo   = (ushortT*)(ws + OFF_WBO);
  ushortT* wt2   = (ushortT*)(ws + OFF_WT2);
  ushortT* wt3   = (ushortT*)(ws + OFF_WT3);
  ushortT* wc1   = (ushortT*)(ws + OFF_WC1);
  ushortT* gb1   = (ushortT*)(ws + OFF_GB1);
  ushortT* gb2   = (ushortT*)(ws + OFF_GB2);

  prep_kernel<<<3152, 256, 0, stream>>>(conv2_w, wt2, conv3_w, wt3, conv1_w, wc1,
                                        Wq, wbq, Wk, wbk, Wv, wbv, out_w, wbo,
                                        gamma1, gb1, gamma2, gb2);
  conv1_mfma_kernel<<<256, 256, 0, stream>>>(x_p, wc1, conv1_b, t1bf);
  gdn_mfma_kernel<<<1024, 256, 0, stream>>>(t1bf, gb1, beta1, x2bf, 1024, 16, 1);
  conv_mfma_kernel<0><<<512, 256, 0, stream>>>(x2bf, wt2, conv2_b, t2bf);
  gdn_mfma_kernel<<<256, 256, 0, stream>>>(t2bf, gb2, beta2, x3bf, 256, 4, 0);
  conv_mfma_kernel<1><<<768, 256, 0, stream>>>(x3bf, wt3, conv3_b, qrawb);
  attn_mega_kernel<<<512, 256, 0, stream>>>(qrawb, ln_q_w, ln_q_b, y_g,
                                            ln_kv_w, ln_kv_b, wbq, wbk, wbv,
                                            wbo, v_w, out_b, ln_out_w,
                                            ln_out_b, out);
}

// Round 11
// 254.110 us; speedup vs baseline: 1.0531x; 1.0343x over previous
//
#include <hip/hip_runtime.h>
#include <cstddef>
#include <cstdint>

// ---------------------------------------------------------------------------
// Pipeline: x (64,3,64,64) -> conv1 5x5s2 (MFMA polyphase) -> GDN1 (MFMA)
//   -> conv2 5x5s2 (MFMA polyphase) -> GDN2 (MFMA) -> conv3 3x3 (MFMA, bf16)
//   -> attn_mega v3 (32-row q tiles, grid 512): coalesced kv stage, fp32
//      energy staging, PV via MFMA, merged projection phase.  7 launches.
// ---------------------------------------------------------------------------

typedef __bf16 bf16x8 __attribute__((ext_vector_type(8)));
typedef float floatx4 __attribute__((ext_vector_type(4)));
typedef unsigned short ushortT;
typedef unsigned short ushort8v __attribute__((ext_vector_type(8)));

#if __has_builtin(__builtin_amdgcn_exp2f)
#define EXP2F(x) __builtin_amdgcn_exp2f(x)
#else
#define EXP2F(x) exp2f(x)
#endif
#if __has_builtin(__builtin_amdgcn_rcpf)
#define RCPF(x) __builtin_amdgcn_rcpf(x)
#else
#define RCPF(x) (1.f / (x))
#endif

__device__ __forceinline__ ushortT f2bf(float f) {
  unsigned u = __builtin_bit_cast(unsigned, f);
  unsigned r = (u + 0x7FFFu + ((u >> 16) & 1u)) >> 16;
  return (ushortT)r;
}
__device__ __forceinline__ float bf2f(ushortT u) {
  return __builtin_bit_cast(float, ((unsigned)u) << 16);
}

// ---- workspace layout (float-slot offsets) ----
static constexpr size_t OFF_T1BF = 0;          // conv1 out bf16 (64,1024,128)
static constexpr size_t OFF_X2BF = 4194304;    // gdn1 out bf16 [b][4][256][128]
static constexpr size_t OFF_T2BF = 8388608;    // conv2 out bf16 (64,256,128)
static constexpr size_t OFF_X3BF = 9437184;    // gdn2 out bf16 (64,256,128)
static constexpr size_t OFF_QRAW = 10485760;   // conv3 out bf16 (64,256,192)
static constexpr size_t OFF_WBQ  = 21299200;   // bf16 128x192 (scaled by c)
static constexpr size_t OFF_WBK  = 21311488;   // bf16 128x192 (scaled by c)
static constexpr size_t OFF_WBV  = 21323776;   // bf16 192x192
static constexpr size_t OFF_WBO  = 21342208;   // bf16 192x192
static constexpr size_t OFF_WT2  = 26079232;   // bf16 conv2 slabs [200][2048]
static constexpr size_t OFF_WT3  = 26284032;   // bf16 conv3 slabs [108][2048]
static constexpr size_t OFF_WC1  = 26394624;   // bf16 conv1 slabs [5][128][32]
static constexpr size_t OFF_GB1  = 26406912;   // bf16 gamma1 128x128
static constexpr size_t OFF_GB2  = 26415104;   // bf16 gamma2 128x128

// 5x5 s2 p2 polyphase tap tables (tap id = kh*5+kw); HW-verified via conv2.
__device__ __constant__ int d_TWI2[4][9] = {{ 0, 2, 4,10,12,14,20,22,24},
                                            { 1, 3,11,13,21,23, 0, 0, 0},
                                            { 5, 7, 9,15,17,19, 0, 0, 0},
                                            { 6, 8,16,18, 0, 0, 0, 0, 0}};
__device__ __constant__ int d_NT2[4] = {9, 6, 6, 4};

// ---------------------------------------------------------------------------
// fused prep: all weight repacks/casts in one launch, block-range dispatch.
// ---------------------------------------------------------------------------
__device__ void dev_convw3(const float* w, ushortT* wt, int mode, int total,
                           int idx) {
  if (idx >= total) return;
  int j    = idx & 7;
  int om   = (idx >> 3) & 63;
  int kg   = (idx >> 9) & 3;
  int slab = idx >> 11;
  int mt, s, tap, T;
  if (mode == 0) {
    int ph;
    if (slab < 72) ph = 0; else if (slab < 120) ph = 1;
    else if (slab < 168) ph = 2; else ph = 3;
    const int st[4] = {0, 72, 120, 168};
    const int ns[4] = {36, 24, 24, 16};
    int rel = slab - st[ph];
    mt = rel / ns[ph]; s = rel % ns[ph];
    tap = d_TWI2[ph][s >> 2]; T = 25;
  } else {
    mt = slab / 36; s = slab % 36; tap = s >> 2; T = 9;
  }
  int cc = s & 3;
  int c  = cc * 32 + kg * 8 + j;
  int oc = mt * 64 + om;
  wt[idx] = f2bf(w[(size_t)(oc * 128 + c) * T + tap]);
}

__device__ void dev_convw1(const float* w, ushortT* wt, int idx) {
  if (idx >= 20480) return;
  int k    = idx & 31;
  int oc   = (idx >> 5) & 127;
  int slab = idx >> 12;
  int ph, i;
  if (slab < 2) { ph = 0; i = slab; } else { ph = slab - 1; i = 0; }
  int kg = k >> 3, jj = k & 7;
  int tidx = i * 8 + jj;
  float val = 0.f;
  if (kg < 3 && tidx < d_NT2[ph]) {
    int tap = d_TWI2[ph][tidx];
    val = w[(size_t)(oc * 3 + kg) * 25 + tap];
  }
  wt[idx] = f2bf(val);
}

__device__ void dev_wcast(const float* w, ushortT* wb, int total, float scale,
                          int idx) {
  if (idx < total) wb[idx] = f2bf(w[idx] * scale);
}

__global__ __launch_bounds__(256) void prep_kernel(
    const float* __restrict__ conv2_w, ushortT* __restrict__ wt2,
    const float* __restrict__ conv3_w, ushortT* __restrict__ wt3,
    const float* __restrict__ conv1_w, ushortT* __restrict__ wc1,
    const float* __restrict__ Wq, ushortT* __restrict__ wbq,
    const float* __restrict__ Wk, ushortT* __restrict__ wbk,
    const float* __restrict__ Wv, ushortT* __restrict__ wbv,
    const float* __restrict__ out_w, ushortT* __restrict__ wbo,
    const float* __restrict__ gamma1, ushortT* __restrict__ gb1,
    const float* __restrict__ gamma2, ushortT* __restrict__ gb2) {
  constexpr float C2LE = 2.88539008177792681f;   // 2*log2(e)
  int blk = blockIdx.x, tid = threadIdx.x;
  if (blk < 1600)      dev_convw3(conv2_w, wt2, 0, 409600, blk * 256 + tid);
  else if (blk < 2464) dev_convw3(conv3_w, wt3, 1, 221184, (blk - 1600) * 256 + tid);
  else if (blk < 2544) dev_convw1(conv1_w, wc1, (blk - 2464) * 256 + tid);
  else if (blk < 2640) dev_wcast(Wq, wbq, 24576, C2LE, (blk - 2544) * 256 + tid);
  else if (blk < 2736) dev_wcast(Wk, wbk, 24576, C2LE, (blk - 2640) * 256 + tid);
  else if (blk < 2880) dev_wcast(Wv, wbv, 36864, 1.f, (blk - 2736) * 256 + tid);
  else if (blk < 3024) dev_wcast(out_w, wbo, 36864, 1.f, (blk - 2880) * 256 + tid);
  else if (blk < 3088) dev_wcast(gamma1, gb1, 16384, 1.f, (blk - 3024) * 256 + tid);
  else                 dev_wcast(gamma2, gb2, 16384, 1.f, (blk - 3088) * 256 + tid);
}

// ---------------------------------------------------------------------------
// conv1 MFMA polyphase: (64,3,64,64) fp32 -> (64,1024px,128c) bf16.
// ---------------------------------------------------------------------------
__global__ __launch_bounds__(256, 1) void conv1_mfma_kernel(
    const float* __restrict__ x, const ushortT* __restrict__ wc1,
    const float* __restrict__ bias, ushortT* __restrict__ outb) {
  int b  = blockIdx.x >> 2;
  int yg = blockIdx.x & 3;
  int y0 = yg * 8;

  int wave = threadIdx.x >> 6;
  int lane = threadIdx.x & 63;
  int ln15 = lane & 15;
  int kg   = lane >> 4;
  int tid  = threadIdx.x;

  __shared__ ushortT simg[4680];
  __shared__ ushortT sA[5 * 128 * 40];

  for (int j = tid; j < 2340; j += 256) ((unsigned*)simg)[j] = 0u;
  __syncthreads();

  int ihBase = 2 * y0 - 2;
  const float* xb = x + (size_t)b * 3 * 4096;
  for (int j = tid; j < 960; j += 256) {
    int q = j & 15;
    int rr = j >> 4;
    int c = rr / 20, ihl = rr % 20;
    int ih = ihBase + ihl;
    if (ih >= 0 && ih < 64) {
      float4 v = *(const float4*)&xb[c * 4096 + ih * 64 + q * 4];
      int pr = ih & 1, u = ih >> 1;
      int lr = u - y0 + 1;
      int base0 = ((pr * 2 + 0) * 3 + c) * 360 + lr * 36;
      int base1 = ((pr * 2 + 1) * 3 + c) * 360 + lr * 36;
      simg[base0 + 2 * q + 1] = f2bf(v.x);
      simg[base1 + 2 * q + 1] = f2bf(v.y);
      simg[base0 + 2 * q + 2] = f2bf(v.z);
      simg[base1 + 2 * q + 2] = f2bf(v.w);
    }
  }
  for (int j = tid; j < 2560; j += 256) {
    int chunk = j & 3, row = j >> 2;
    uint4 v = *(const uint4*)&wc1[row * 32 + chunk * 8];
    *(uint4*)&sA[row * 40 + chunk * 8] = v;
  }
  __syncthreads();

  constexpr int TDR[4][9] = {{-1,-1,-1, 0, 0, 0, 1, 1, 1},
                             {-1,-1, 0, 0, 1, 1, 0, 0, 0},
                             {-1,-1,-1, 0, 0, 0, 0, 0, 0},
                             {-1,-1, 0, 0, 0, 0, 0, 0, 0}};
  constexpr int TDC[4][9] = {{-1, 0, 1,-1, 0, 1,-1, 0, 1},
                             {-1, 0,-1, 0,-1, 0, 0, 0, 0},
                             {-1, 0, 1,-1, 0, 1, 0, 0, 0},
                             {-1, 0,-1, 0, 0, 0, 0, 0, 0}};
  constexpr int NT[4]  = {9, 6, 6, 4};
  constexpr int NM[4]  = {2, 1, 1, 1};
  constexpr int SB[4]  = {0, 2, 3, 4};

  ushort8v Bf[4][5];
  #pragma unroll
  for (int ntl = 0; ntl < 4; ++ntl) {
    int ntg = wave * 4 + ntl;
    int yloc = ntg >> 1;
    int xx = (ntg & 1) * 16 + ln15;
    int lbase = (yloc + 1) * 36 + xx + 1 + kg * 360;
    #pragma unroll
    for (int ph = 0; ph < 4; ++ph) {
      int pbase = ph * 1080 + lbase;
      #pragma unroll
      for (int i = 0; i < 2; ++i) {
        if (i < NM[ph]) {
          ushort8v bv;
          #pragma unroll
          for (int j = 0; j < 8; ++j) {
            int tidx = i * 8 + j;
            if (tidx >= NT[ph]) tidx = 0;
            int off = TDR[ph][tidx] * 36 + TDC[ph][tidx];
            bv[j] = simg[pbase + off];
          }
          Bf[ntl][SB[ph] + i] = bv;
        }
      }
    }
  }

  #pragma unroll
  for (int m = 0; m < 8; ++m) {
    bf16x8 Af[5];
    #pragma unroll
    for (int s = 0; s < 5; ++s)
      Af[s] = *(const bf16x8*)&sA[(s * 128 + m * 16 + ln15) * 40 + kg * 8];
    int oc0 = m * 16 + kg * 4;
    float4 bv = *(const float4*)&bias[oc0];
    #pragma unroll
    for (int ntl = 0; ntl < 4; ++ntl) {
      floatx4 acc = (floatx4)0.f;
      #pragma unroll
      for (int s = 0; s < 5; ++s)
        acc = __builtin_amdgcn_mfma_f32_16x16x32_bf16(
            Af[s], __builtin_bit_cast(bf16x8, Bf[ntl][s]), acc, 0, 0, 0);
      int ntg = wave * 4 + ntl;
      int y = y0 + (ntg >> 1);
      int xx = (ntg & 1) * 16 + ln15;
      int p = y * 32 + xx;
      ushort4 o4 = {f2bf(acc[0] + bv.x), f2bf(acc[1] + bv.y),
                    f2bf(acc[2] + bv.z), f2bf(acc[3] + bv.w)};
      *(ushort4*)&outb[((size_t)b * 1024 + p) * 128 + oc0] = o4;
    }
  }
}

// ---------------------------------------------------------------------------
// GDN as bf16 MFMA GEMM.
// ---------------------------------------------------------------------------
__global__ __launch_bounds__(256) void gdn_mfma_kernel(
    const ushortT* __restrict__ xbf, const ushortT* __restrict__ gb,
    const float* __restrict__ beta, ushortT* __restrict__ ybf,
    int HW, int nPixTiles, int isSplit) {
  int pt = blockIdx.x % nPixTiles;
  int b  = blockIdx.x / nPixTiles;
  int px0 = pt * 64;
  int tid = threadIdx.x;
  int wave = tid >> 6, lane = tid & 63, ln15 = lane & 15, kg = lane >> 4;

  __shared__ ushortT sG[128 * 136];
  __shared__ ushortT sX[64 * 136];

  for (int j = tid; j < 2048; j += 256) {
    int row = j >> 4, ch = j & 15;
    *(uint4*)&sG[row * 136 + ch * 8] = *(const uint4*)&gb[row * 128 + ch * 8];
  }
  for (int j = tid; j < 1024; j += 256) {
    int row = j >> 4, ch = j & 15;
    ushort8v xv = *(const ushort8v*)&xbf[((size_t)(b * HW + px0 + row)) * 128 + ch * 8];
    ushort8v sq;
    #pragma unroll
    for (int r = 0; r < 8; ++r) {
      float f = bf2f(xv[r]);
      sq[r] = f2bf(f * f);
    }
    *(ushort8v*)&sX[row * 136 + ch * 8] = sq;
  }
  __syncthreads();

  floatx4 acc[2][4];
  #pragma unroll
  for (int mi = 0; mi < 2; ++mi)
    #pragma unroll
    for (int nt = 0; nt < 4; ++nt) acc[mi][nt] = (floatx4)0.f;

  #pragma unroll
  for (int k0 = 0; k0 < 128; k0 += 32) {
    bf16x8 a0 = *(const bf16x8*)&sG[(wave * 32 + ln15) * 136 + k0 + kg * 8];
    bf16x8 a1 = *(const bf16x8*)&sG[(wave * 32 + 16 + ln15) * 136 + k0 + kg * 8];
    #pragma unroll
    for (int nt = 0; nt < 4; ++nt) {
      bf16x8 bb = *(const bf16x8*)&sX[(nt * 16 + ln15) * 136 + k0 + kg * 8];
      acc[0][nt] = __builtin_amdgcn_mfma_f32_16x16x32_bf16(a0, bb, acc[0][nt], 0, 0, 0);
      acc[1][nt] = __builtin_amdgcn_mfma_f32_16x16x32_bf16(a1, bb, acc[1][nt], 0, 0, 0);
    }
  }

  #pragma unroll
  for (int mi = 0; mi < 2; ++mi) {
    int d0 = wave * 32 + mi * 16 + kg * 4;
    float4 bt = *(const float4*)&beta[d0];
    #pragma unroll
    for (int nt = 0; nt < 4; ++nt) {
      int p = px0 + nt * 16 + ln15;
      ushort4 x4 = *(const ushort4*)&xbf[((size_t)(b * HW + p)) * 128 + d0];
      ushort4 o4;
      o4.x = f2bf(bf2f(x4.x) * rsqrtf(acc[mi][nt][0] + bt.x));
      o4.y = f2bf(bf2f(x4.y) * rsqrtf(acc[mi][nt][1] + bt.y));
      o4.z = f2bf(bf2f(x4.z) * rsqrtf(acc[mi][nt][2] + bt.z));
      o4.w = f2bf(bf2f(x4.w) * rsqrtf(acc[mi][nt][3] + bt.w));
      size_t dst;
      if (isSplit) {
        int h = p >> 5, w5 = p & 31;
        int ph = ((h & 1) << 1) | (w5 & 1);
        dst = (((size_t)b * 4 + ph) * 256 + (h >> 1) * 16 + (w5 >> 1)) * 128 + d0;
      } else {
        dst = ((size_t)b * 256 + p) * 128 + d0;
      }
      *(ushort4*)&ybf[dst] = o4;
    }
  }
}

// ---------------------------------------------------------------------------
// conv2/conv3 MFMA implicit GEMM; 4-row split, 2 blocks/CU, bf16 out.
// ---------------------------------------------------------------------------
template<int MODE>
__global__ __launch_bounds__(256, 2) void conv_mfma_kernel(
    const ushortT* __restrict__ X,
    const ushortT* __restrict__ Wt,
    const float* __restrict__ bias,
    ushortT* __restrict__ outb) {
  constexpr int OC  = (MODE == 0) ? 128 : 192;
  constexpr int NMT = OC / 64;
  constexpr int NPH = (MODE == 0) ? 4 : 1;

  int b   = blockIdx.x / (NMT * 4);
  int rem = blockIdx.x % (NMT * 4);
  int mt  = rem >> 2;
  int rs  = rem & 3;
  int r0  = rs * 4;

  int wave = threadIdx.x >> 6;
  int lane = threadIdx.x & 63;
  int ln15 = lane & 15;
  int kg   = lane >> 4;

  __shared__ ushortT simg[6 * 18 * 136];

  floatx4 acc[4];
  #pragma unroll
  for (int m = 0; m < 4; ++m) acc[m] = (floatx4)0.f;

  constexpr int NS2[4]      = {36, 24, 24, 16};
  constexpr int PHSTART2[4] = {0, 72, 120, 168};
  constexpr int TDR_2[4][9] = {{-1,-1,-1, 0, 0, 0, 1, 1, 1},
                               {-1,-1, 0, 0, 1, 1, 0, 0, 0},
                               {-1,-1,-1, 0, 0, 0, 0, 0, 0},
                               {-1,-1, 0, 0, 0, 0, 0, 0, 0}};
  constexpr int TDC_2[4][9] = {{-1, 0, 1,-1, 0, 1,-1, 0, 1},
                               {-1, 0,-1, 0,-1, 0, 0, 0, 0},
                               {-1, 0, 1,-1, 0, 1, 0, 0, 0},
                               {-1, 0,-1, 0, 0, 0, 0, 0, 0}};
  constexpr int TDR_3[9] = {-1,-1,-1, 0, 0, 0, 1, 1, 1};
  constexpr int TDC_3[9] = {-1, 0, 1,-1, 0, 1,-1, 0, 1};

  const int aoff = kg * 512 + ln15 * 8;
  uint4 apf[8][4];

  #pragma unroll
  for (int ph = 0; ph < NPH; ++ph) {
    const int NS = (MODE == 0) ? NS2[ph] : 36;
    const int slabBase = (MODE == 0) ? (PHSTART2[ph] + mt * NS2[ph]) : (mt * 36);
    const ushortT* wp0 = Wt + (size_t)slabBase * 2048 + aoff;

    __syncthreads();
    const ushortT* Xb = X + (((size_t)b * NPH + ph) * 256) * 128;
    for (int idx = threadIdx.x; idx < 1728; idx += 256) {
      int chunk = idx & 15;
      int pix = idx >> 4;
      int row = pix / 18, colm = pix - row * 18;
      int i = r0 - 1 + row, j = colm - 1;
      uint4 v = {0u, 0u, 0u, 0u};
      if (i >= 0 && i < 16 && j >= 0 && j < 16)
        v = *(const uint4*)(Xb + ((size_t)(i * 16 + j)) * 128 + chunk * 8);
      *(uint4*)&simg[(row * 18 + colm) * 136 + chunk * 8] = v;
    }
    #pragma unroll
    for (int jj = 0; jj < 8; ++jj)
      if (jj < NS) {
        #pragma unroll
        for (int m = 0; m < 4; ++m)
          apf[jj][m] = *(const uint4*)(wp0 + (size_t)jj * 2048 + m * 128);
      }
    __syncthreads();

    #pragma unroll
    for (int s0 = 0; s0 < NS; s0 += 8) {
      #pragma unroll
      for (int jj = 0; jj < 8; ++jj) {
        int s = s0 + jj;
        if (s < NS) {
          bf16x8 acur[4];
          #pragma unroll
          for (int m = 0; m < 4; ++m) acur[m] = __builtin_bit_cast(bf16x8, apf[jj][m]);
          int sp = s + 8;
          if (sp < NS) {
            #pragma unroll
            for (int m = 0; m < 4; ++m)
              apf[jj][m] = *(const uint4*)(wp0 + (size_t)sp * 2048 + m * 128);
          }
          int t  = s >> 2;
          int c0 = (s & 3) * 32;
          int dr = (MODE == 0) ? TDR_2[ph][t] : TDR_3[t];
          int dc = (MODE == 0) ? TDC_2[ph][t] : TDC_3[t];
          int lrow = wave + dr + 1;
          int lcol = ln15 + dc + 1;
          bf16x8 bfr = *(const bf16x8*)&simg[(lrow * 18 + lcol) * 136 + c0 + kg * 8];
          #pragma unroll
          for (int m = 0; m < 4; ++m)
            acc[m] = __builtin_amdgcn_mfma_f32_16x16x32_bf16(acur[m], bfr, acc[m], 0, 0, 0);
        }
      }
    }
  }

  #pragma unroll
  for (int m = 0; m < 4; ++m) {
    int mg = mt * 64 + m * 16 + kg * 4;
    float4 bv = *(const float4*)&bias[mg];
    int r = r0 + wave;
    int p = r * 16 + ln15;
    ushort4 o4 = {f2bf(acc[m][0] + bv.x), f2bf(acc[m][1] + bv.y),
                  f2bf(acc[m][2] + bv.z), f2bf(acc[m][3] + bv.w)};
    *(ushort4*)&outb[((size_t)b * 256 + p) * OC + mg] = o4;
  }
}

// ---------------------------------------------------------------------------
// attn_mega v3: 32-row q tiles, grid 512, ~75.3KB LDS -> 2 blocks/CU.
// Phase-overlaid LDS (ushort offsets):
//   SQLN   [0,6400)       bf16 [32][200]  ph0-2
//   SKV    [6400,12800)   bf16 [32][200]  ph1-2
//   SKVRAW [12800,25216)  f32  [32][194]  ph0-1 (coalesced yg stage)
//   SQPF   [12800,21248)  f32  [32][132]  ph2-3
//   SKPF   [21248,29696)  f32  [32][132]  ph2-3
//   SVPT   [29696,37376)  bf16 [192][40]  ph2-5 (V transposed for PV MFMA)
//   SWM    [37376,37632)  f32  [128]
//   S0     [37632,37634)  f32
//   SE     [6400,8704)    f32  [32][36]   ph3-5 (over dead SKV)
//   SCTX   [12800,19200)  bf16 [32][200]  ph5-6 (over dead SQPF)
//   SF     [21248,33600)  f32  [32][193]  ph6   (over dead SKPF/SVPT)
// ---------------------------------------------------------------------------
__global__ __launch_bounds__(256) void attn_mega_kernel(
    const ushortT* __restrict__ qrawb, const float* __restrict__ ln_q_w,
    const float* __restrict__ ln_q_b, const float* __restrict__ yg,
    const float* __restrict__ ln_kv_w, const float* __restrict__ ln_kv_b,
    const ushortT* __restrict__ wbq, const ushortT* __restrict__ wbk,
    const ushortT* __restrict__ wbv, const ushortT* __restrict__ wbo,
    const float* __restrict__ vw, const float* __restrict__ out_b,
    const float* __restrict__ ln_out_w, const float* __restrict__ ln_out_b,
    float* __restrict__ out) {
  __shared__ ushortT smem[37640];
  ushortT* sqln   = smem;
  ushortT* skv    = smem + 6400;
  float*   skvRaw = (float*)(smem + 12800);
  float*   sqpF   = (float*)(smem + 12800);
  float*   skpF   = (float*)(smem + 21248);
  ushortT* svpT   = smem + 29696;
  float*   swm    = (float*)(smem + 37376);
  float*   sS0    = (float*)(smem + 37632);
  float*   se     = (float*)(smem + 6400);
  ushortT* sctx   = smem + 12800;
  float*   sf     = (float*)(smem + 21248);

  int b  = blockIdx.x >> 3;
  int t0 = (blockIdx.x & 7) * 32;
  int tid  = threadIdx.x;
  int wave = tid >> 6;
  int lane = tid & 63;
  int ln15 = lane & 15;
  int kg   = lane >> 4;

  // ---- ph0: coalesced yg stage -> skvRaw; LN(q rows) -> sqln; swm/S0 ----
  {
    const float4* yg4 = (const float4*)(yg + (size_t)b * 6144);
    for (int j = tid; j < 1536; j += 256) {
      float4 v = yg4[j];
      int c = j >> 3;              // channel (0..191)
      int t4 = (j & 7) * 4;        // t base (0..28)
      skvRaw[(t4 + 0) * 194 + c] = v.x;
      skvRaw[(t4 + 1) * 194 + c] = v.y;
      skvRaw[(t4 + 2) * 194 + c] = v.z;
      skvRaw[(t4 + 3) * 194 + c] = v.w;
    }
  }
  for (int r = wave; r < 32; r += 4) {
    const ushortT* xr = qrawb + ((size_t)(b * 256 + t0 + r)) * 192;
    float v0 = bf2f(xr[lane]), v1 = bf2f(xr[lane + 64]), v2 = bf2f(xr[lane + 128]);
    float s = v0 + v1 + v2;
    float s2 = v0 * v0 + v1 * v1 + v2 * v2;
    #pragma unroll
    for (int off = 32; off; off >>= 1) { s += __shfl_xor(s, off); s2 += __shfl_xor(s2, off); }
    float mean = s * (1.f / 192.f);
    float var = s2 * (1.f / 192.f) - mean * mean;
    float inv = rsqrtf(var + 1e-5f);
    sqln[r * 200 + lane]       = f2bf((v0 - mean) * inv * ln_q_w[lane]       + ln_q_b[lane]);
    sqln[r * 200 + lane + 64]  = f2bf((v1 - mean) * inv * ln_q_w[lane + 64]  + ln_q_b[lane + 64]);
    sqln[r * 200 + lane + 128] = f2bf((v2 - mean) * inv * ln_q_w[lane + 128] + ln_q_b[lane + 128]);
  }
  if (tid < 128) swm[tid] = -2.f * vw[tid];
  if (tid >= 128 && tid < 192) {
    int l = tid - 128;
    float s = vw[l] + vw[l + 64];
    #pragma unroll
    for (int off = 32; off; off >>= 1) s += __shfl_xor(s, off);
    if (l == 0) *sS0 = s;
  }
  __syncthreads();

  // ---- ph1: kv LN (from skvRaw) -> skv ----
  for (int r = wave; r < 32; r += 4) {
    const float* src = skvRaw + r * 194;
    float v0 = src[lane], v1 = src[lane + 64], v2 = src[lane + 128];
    float s = v0 + v1 + v2;
    float s2 = v0 * v0 + v1 * v1 + v2 * v2;
    #pragma unroll
    for (int off = 32; off; off >>= 1) { s += __shfl_xor(s, off); s2 += __shfl_xor(s2, off); }
    float mean = s * (1.f / 192.f);
    float var = s2 * (1.f / 192.f) - mean * mean;
    float inv = rsqrtf(var + 1e-5f);
    skv[r * 200 + lane]       = f2bf((v0 - mean) * inv * ln_kv_w[lane]       + ln_kv_b[lane]);
    skv[r * 200 + lane + 64]  = f2bf((v1 - mean) * inv * ln_kv_w[lane + 64]  + ln_kv_b[lane + 64]);
    skv[r * 200 + lane + 128] = f2bf((v2 - mean) * inv * ln_kv_w[lane + 128] + ln_kv_b[lane + 128]);
  }
  __syncthreads();

  // ---- ph2: merged projections: q -> sqpF, k -> skpF, v -> svpT (transposed)
  for (int ti = wave; ti < 56; ti += 4) {
    floatx4 acc = (floatx4)0.f;
    if (ti < 16) {                 // qproj: rt in {0,1}, ct in {0..7}
      int rt = ti >> 3, ct = ti & 7;
      #pragma unroll
      for (int k0 = 0; k0 < 192; k0 += 32) {
        bf16x8 afr = *(const bf16x8*)&sqln[(rt * 16 + ln15) * 200 + k0 + kg * 8];
        bf16x8 bfr = *(const bf16x8*)&wbq[((size_t)(ct * 16 + ln15)) * 192 + k0 + kg * 8];
        acc = __builtin_amdgcn_mfma_f32_16x16x32_bf16(afr, bfr, acc, 0, 0, 0);
      }
      #pragma unroll
      for (int r = 0; r < 4; ++r)
        sqpF[(rt * 16 + kg * 4 + r) * 132 + ct * 16 + ln15] = acc[r];
    } else if (ti < 32) {          // kproj
      int t2 = ti - 16;
      int rt = t2 >> 3, ct = t2 & 7;
      #pragma unroll
      for (int k0 = 0; k0 < 192; k0 += 32) {
        bf16x8 afr = *(const bf16x8*)&skv[(rt * 16 + ln15) * 200 + k0 + kg * 8];
        bf16x8 bfr = *(const bf16x8*)&wbk[((size_t)(ct * 16 + ln15)) * 192 + k0 + kg * 8];
        acc = __builtin_amdgcn_mfma_f32_16x16x32_bf16(afr, bfr, acc, 0, 0, 0);
      }
      #pragma unroll
      for (int r = 0; r < 4; ++r)
        skpF[(rt * 16 + kg * 4 + r) * 132 + ct * 16 + ln15] = acc[r];
    } else {                       // vproj -> transposed store
      int t2 = ti - 32;
      int rt = t2 / 12, ct = t2 % 12;
      #pragma unroll
      for (int k0 = 0; k0 < 192; k0 += 32) {
        bf16x8 afr = *(const bf16x8*)&skv[(rt * 16 + ln15) * 200 + k0 + kg * 8];
        bf16x8 bfr = *(const bf16x8*)&wbv[((size_t)(ct * 16 + ln15)) * 192 + k0 + kg * 8];
        acc = __builtin_amdgcn_mfma_f32_16x16x32_bf16(afr, bfr, acc, 0, 0, 0);
      }
      #pragma unroll
      for (int r = 0; r < 4; ++r)
        svpT[(ct * 16 + ln15) * 40 + rt * 16 + kg * 4 + r] = f2bf(acc[r]);
    }
  }
  __syncthreads();

  // ---- ph3: energy (fp32, no conversions) -> se [32][36] ----
  {
    float S0v = *sS0;
    int qq0 = tid >> 4, kc = tid & 15;
    const float4* w4 = (const float4*)swm;
    #pragma unroll
    for (int st = 0; st < 2; ++st) {
      int qq = st * 16 + qq0;
      const float4* q4 = (const float4*)&sqpF[qq * 132];
      const float4* ka = (const float4*)&skpF[kc * 132];
      const float4* kb = (const float4*)&skpF[(kc + 16) * 132];
      float acc0 = S0v, acc1 = S0v;
      #pragma unroll 8
      for (int d4 = 0; d4 < 32; ++d4) {
        float4 qv = q4[d4], k0v = ka[d4], k1v = kb[d4], wv = w4[d4];
        acc0 += wv.x * RCPF(EXP2F(qv.x + k0v.x) + 1.f);
        acc0 += wv.y * RCPF(EXP2F(qv.y + k0v.y) + 1.f);
        acc0 += wv.z * RCPF(EXP2F(qv.z + k0v.z) + 1.f);
        acc0 += wv.w * RCPF(EXP2F(qv.w + k0v.w) + 1.f);
        acc1 += wv.x * RCPF(EXP2F(qv.x + k1v.x) + 1.f);
        acc1 += wv.y * RCPF(EXP2F(qv.y + k1v.y) + 1.f);
        acc1 += wv.z * RCPF(EXP2F(qv.z + k1v.z) + 1.f);
        acc1 += wv.w * RCPF(EXP2F(qv.w + k1v.w) + 1.f);
      }
      se[qq * 36 + kc] = acc0;
      se[qq * 36 + kc + 16] = acc1;
    }
  }
  __syncthreads();

  // ---- ph4: softmax rows ----
  if (tid < 32) {
    float* ser = se + tid * 36;
    float mx = -1e30f;
    for (int k = 0; k < 32; ++k) mx = fmaxf(mx, ser[k]);
    float s = 0.f;
    for (int k = 0; k < 32; ++k) { float a = __expf(ser[k] - mx); ser[k] = a; s += a; }
    float invs = 1.f / s;
    for (int k = 0; k < 32; ++k) ser[k] *= invs;
  }
  __syncthreads();

  // ---- ph5: PV via MFMA (P from se bf16 A-frags, V^T B-frags) -> sctx ----
  for (int ti = wave; ti < 24; ti += 4) {
    int rt = ti / 12, ct = ti % 12;
    float4 a0 = *(const float4*)&se[(rt * 16 + ln15) * 36 + kg * 8];
    float4 a1 = *(const float4*)&se[(rt * 16 + ln15) * 36 + kg * 8 + 4];
    ushort8v au;
    au[0] = f2bf(a0.x); au[1] = f2bf(a0.y); au[2] = f2bf(a0.z); au[3] = f2bf(a0.w);
    au[4] = f2bf(a1.x); au[5] = f2bf(a1.y); au[6] = f2bf(a1.z); au[7] = f2bf(a1.w);
    bf16x8 bfr = *(const bf16x8*)&svpT[(ct * 16 + ln15) * 40 + kg * 8];
    floatx4 acc = __builtin_amdgcn_mfma_f32_16x16x32_bf16(
        __builtin_bit_cast(bf16x8, au), bfr, (floatx4)0.f, 0, 0, 0);
    #pragma unroll
    for (int r = 0; r < 4; ++r)
      sctx[(rt * 16 + kg * 4 + r) * 200 + ct * 16 + ln15] = f2bf(acc[r]);
  }
  __syncthreads();

  // ---- ph6: outproj -> sf ----
  for (int ti = wave; ti < 24; ti += 4) {
    int rt = ti / 12, ct = ti % 12;
    floatx4 acc = (floatx4)0.f;
    #pragma unroll
    for (int k0 = 0; k0 < 192; k0 += 32) {
      bf16x8 afr = *(const bf16x8*)&sctx[(rt * 16 + ln15) * 200 + k0 + kg * 8];
      bf16x8 bfr = *(const bf16x8*)&wbo[((size_t)(ct * 16 + ln15)) * 192 + k0 + kg * 8];
      acc = __builtin_amdgcn_mfma_f32_16x16x32_bf16(afr, bfr, acc, 0, 0, 0);
    }
    float bv = out_b[ct * 16 + ln15];
    #pragma unroll
    for (int r = 0; r < 4; ++r)
      sf[(rt * 16 + kg * 4 + r) * 193 + ct * 16 + ln15] = acc[r] + bv;
  }
  __syncthreads();

  // ---- ph7: residual (recompute q-LN) + final LN, then transpose store ----
  for (int rr = wave; rr < 32; rr += 4) {
    int t = t0 + rr;
    const ushortT* xr = qrawb + ((size_t)(b * 256 + t)) * 192;
    float r0_ = bf2f(xr[lane]), r1_ = bf2f(xr[lane + 64]), r2_ = bf2f(xr[lane + 128]);
    float s = r0_ + r1_ + r2_;
    float s2 = r0_ * r0_ + r1_ * r1_ + r2_ * r2_;
    #pragma unroll
    for (int off = 32; off; off >>= 1) { s += __shfl_xor(s, off); s2 += __shfl_xor(s2, off); }
    float mean = s * (1.f / 192.f);
    float var = s2 * (1.f / 192.f) - mean * mean;
    float inv = rsqrtf(var + 1e-5f);
    float q0 = (r0_ - mean) * inv * ln_q_w[lane]       + ln_q_b[lane];
    float q1 = (r1_ - mean) * inv * ln_q_w[lane + 64]  + ln_q_b[lane + 64];
    float q2 = (r2_ - mean) * inv * ln_q_w[lane + 128] + ln_q_b[lane + 128];
    float v0 = sf[rr * 193 + lane]       + q0;
    float v1 = sf[rr * 193 + lane + 64]  + q1;
    float v2 = sf[rr * 193 + lane + 128] + q2;
    float t_s = v0 + v1 + v2;
    float t_s2 = v0 * v0 + v1 * v1 + v2 * v2;
    #pragma unroll
    for (int off = 32; off; off >>= 1) { t_s += __shfl_xor(t_s, off); t_s2 += __shfl_xor(t_s2, off); }
    float m2 = t_s * (1.f / 192.f);
    float var2 = t_s2 * (1.f / 192.f) - m2 * m2;
    float inv2 = rsqrtf(var2 + 1e-5f);
    sf[rr * 193 + lane]       = (v0 - m2) * inv2 * ln_out_w[lane]       + ln_out_b[lane];
    sf[rr * 193 + lane + 64]  = (v1 - m2) * inv2 * ln_out_w[lane + 64]  + ln_out_b[lane + 64];
    sf[rr * 193 + lane + 128] = (v2 - m2) * inv2 * ln_out_w[lane + 128] + ln_out_b[lane + 128];
  }
  __syncthreads();

  for (int j = tid; j < 1536; j += 256) {
    int m = j >> 3, t4 = j & 7;
    float4 o4;
    o4.x = sf[(t4 * 4 + 0) * 193 + m];
    o4.y = sf[(t4 * 4 + 1) * 193 + m];
    o4.z = sf[(t4 * 4 + 2) * 193 + m];
    o4.w = sf[(t4 * 4 + 3) * 193 + m];
    *(float4*)&out[((size_t)(b * 192 + m)) * 256 + t0 + t4 * 4] = o4;
  }
}

// ---------------------------------------------------------------------------
extern "C" void kernel_launch(void* const* d_in, const int* in_sizes, int n_in,
                              void* d_out, int out_size, void* d_ws, size_t ws_size,
                              hipStream_t stream) {
  (void)in_sizes; (void)n_in; (void)out_size; (void)ws_size;
  const float* x_p     = (const float*)d_in[0];
  const float* y_g     = (const float*)d_in[1];
  const float* conv1_w = (const float*)d_in[2];
  const float* conv1_b = (const float*)d_in[3];
  const float* gamma1  = (const float*)d_in[4];
  const float* beta1   = (const float*)d_in[5];
  const float* conv2_w = (const float*)d_in[6];
  const float* conv2_b = (const float*)d_in[7];
  const float* gamma2  = (const float*)d_in[8];
  const float* beta2   = (const float*)d_in[9];
  const float* conv3_w = (const float*)d_in[10];
  const float* conv3_b = (const float*)d_in[11];
  const float* ln_q_w  = (const float*)d_in[12];
  const float* ln_q_b  = (const float*)d_in[13];
  const float* ln_kv_w = (const float*)d_in[14];
  const float* ln_kv_b = (const float*)d_in[15];
  const float* ln_out_w= (const float*)d_in[16];
  const float* ln_out_b= (const float*)d_in[17];
  const float* Wq      = (const float*)d_in[18];
  const float* Wk      = (const float*)d_in[19];
  const float* v_w     = (const float*)d_in[20];
  const float* Wv      = (const float*)d_in[21];
  const float* out_w   = (const float*)d_in[22];
  const float* out_b   = (const float*)d_in[23];
  float* out = (float*)d_out;
  float* ws  = (float*)d_ws;

  ushortT* t1bf  = (ushortT*)(ws + OFF_T1BF);
  ushortT* x2bf  = (ushortT*)(ws + OFF_X2BF);
  ushortT* t2bf  = (ushortT*)(ws + OFF_T2BF);
  ushortT* x3bf  = (ushortT*)(ws + OFF_X3BF);
  ushortT* qrawb = (ushortT*)(ws + OFF_QRAW);
  ushortT* wbq   = (ushortT*)(ws + OFF_WBQ);
  ushortT* wbk   = (ushortT*)(ws + OFF_WBK);
  ushortT* wbv   = (ushortT*)(ws + OFF_WBV);
  ushortT* wbo   = (ushortT*)(ws + OFF_WBO);
  ushortT* wt2   = (ushortT*)(ws + OFF_WT2);
  ushortT* wt3   = (ushortT*)(ws + OFF_WT3);
  ushortT* wc1   = (ushortT*)(ws + OFF_WC1);
  ushortT* gb1   = (ushortT*)(ws + OFF_GB1);
  ushortT* gb2   = (ushortT*)(ws + OFF_GB2);

  prep_kernel<<<3152, 256, 0, stream>>>(conv2_w, wt2, conv3_w, wt3, conv1_w, wc1,
                                        Wq, wbq, Wk, wbk, Wv, wbv, out_w, wbo,
                                        gamma1, gb1, gamma2, gb2);
  conv1_mfma_kernel<<<256, 256, 0, stream>>>(x_p, wc1, conv1_b, t1bf);
  gdn_mfma_kernel<<<1024, 256, 0, stream>>>(t1bf, gb1, beta1, x2bf, 1024, 16, 1);
  conv_mfma_kernel<0><<<512, 256, 0, stream>>>(x2bf, wt2, conv2_b, t2bf);
  gdn_mfma_kernel<<<256, 256, 0, stream>>>(t2bf, gb2, beta2, x3bf, 256, 4, 0);
  conv_mfma_kernel<1><<<768, 256, 0, stream>>>(x3bf, wt3, conv3_b, qrawb);
  attn_mega_kernel<<<512, 256, 0, stream>>>(qrawb, ln_q_w, ln_q_b, y_g,
                                            ln_kv_w, ln_kv_b, wbq, wbk, wbv,
                                            wbo, v_w, out_b, ln_out_w,
                                            ln_out_b, out);
}